// Round 7
// baseline (320.947 us; speedup 1.0000x reference)
//
#include <hip/hip_runtime.h>
#include <hip/hip_bf16.h>

#define BB 4
#define CC_ 384
#define HH 32
#define WW 32
#define HWSZ 1024
#define NHD 12
#define HCH 32
#define GG 6
#define NGC_ 64
#define GHD 2
#define HK_ 16
#define WK_ 16
#define NS_ 256
#define RPEW 63
#define SCALE_ 0.17677669529663687f

// ---------------- K1/K6: 1x1 conv, 8 output rows per thread ----------------
template<int CIN>
__global__ void conv1x1_k8(const float* __restrict__ W, const float* __restrict__ bias,
                           const float* __restrict__ X, float* __restrict__ Y,
                           int N, int OC)
{
    const int otile = blockIdx.y * 8;
    const int b = blockIdx.z;
    const int n4 = (blockIdx.x * blockDim.x + threadIdx.x) * 4;
    const float* Xb = X + (size_t)b * CIN * N + n4;
    const float* Wr = W + (size_t)otile * CIN;

    float acc[8][4];
#pragma unroll
    for (int j = 0; j < 8; ++j)
#pragma unroll
        for (int i = 0; i < 4; ++i) acc[j][i] = 0.f;

    for (int c = 0; c < CIN; ++c) {
        float4 xv = *(const float4*)(Xb + (size_t)c * N);
#pragma unroll
        for (int j = 0; j < 8; ++j) {
            float w = Wr[j * CIN + c];
            acc[j][0] = fmaf(w, xv.x, acc[j][0]);
            acc[j][1] = fmaf(w, xv.y, acc[j][1]);
            acc[j][2] = fmaf(w, xv.z, acc[j][2]);
            acc[j][3] = fmaf(w, xv.w, acc[j][3]);
        }
    }
#pragma unroll
    for (int j = 0; j < 8; ++j) {
        int o = otile + j;
        float bv = bias[o];
        float4 r = make_float4(acc[j][0] + bv, acc[j][1] + bv, acc[j][2] + bv, acc[j][3] + bv);
        *(float4*)(Y + ((size_t)(b * OC + o)) * N + n4) = r;
    }
}

// ---------------- K4: fused K+V 1x1 conv, head-transposed outputs [bh][n][32] ----------------
template<int CIN>
__global__ void convkv_kernel(const float* __restrict__ Wk, const float* __restrict__ bk,
                              const float* __restrict__ Wv, const float* __restrict__ bv,
                              const float* __restrict__ X, float* __restrict__ Yk,
                              float* __restrict__ Yv, int N)
{
    const int otile = blockIdx.y * 4;          // 4-aligned => same head
    const int b = blockIdx.z;
    const int n4 = threadIdx.x * 4;
    const float* Xb = X + (size_t)b * CIN * N + n4;
    const float* Wkr = Wk + (size_t)otile * CIN;
    const float* Wvr = Wv + (size_t)otile * CIN;

    float ak[4][4], av[4][4];
#pragma unroll
    for (int j = 0; j < 4; ++j)
#pragma unroll
        for (int i = 0; i < 4; ++i) { ak[j][i] = 0.f; av[j][i] = 0.f; }

    for (int c = 0; c < CIN; ++c) {
        float4 xv = *(const float4*)(Xb + (size_t)c * N);
#pragma unroll
        for (int j = 0; j < 4; ++j) {
            float wk = Wkr[j * CIN + c];
            ak[j][0] = fmaf(wk, xv.x, ak[j][0]);
            ak[j][1] = fmaf(wk, xv.y, ak[j][1]);
            ak[j][2] = fmaf(wk, xv.z, ak[j][2]);
            ak[j][3] = fmaf(wk, xv.w, ak[j][3]);
            float wv = Wvr[j * CIN + c];
            av[j][0] = fmaf(wv, xv.x, av[j][0]);
            av[j][1] = fmaf(wv, xv.y, av[j][1]);
            av[j][2] = fmaf(wv, xv.z, av[j][2]);
            av[j][3] = fmaf(wv, xv.w, av[j][3]);
        }
    }
    const int h = otile >> 5, cc = otile & 31;
    const size_t obase = ((size_t)(b * NHD + h) * N) * 32 + cc;
#pragma unroll
    for (int i = 0; i < 4; ++i) {
        float4 rk = make_float4(ak[0][i] + bk[otile + 0], ak[1][i] + bk[otile + 1],
                                ak[2][i] + bk[otile + 2], ak[3][i] + bk[otile + 3]);
        float4 rv = make_float4(av[0][i] + bv[otile + 0], av[1][i] + bv[otile + 1],
                                av[2][i] + bv[otile + 2], av[3][i] + bv[otile + 3]);
        *(float4*)(Yk + obase + (size_t)(n4 + i) * 32) = rk;
        *(float4*)(Yv + obase + (size_t)(n4 + i) * 32) = rv;
    }
}

// ---------------- K2a: depthwise conv 5x5 stride 2, transposed output [bg][pos][ch] ----------------
__global__ void offset_dw_kernel(const float* __restrict__ qb, const float* __restrict__ dww,
                                 const float* __restrict__ dwb, float* __restrict__ cobuf)
{
    __shared__ float img[HWSZ];
    const int c = blockIdx.x, bg = blockIdx.y;
    const int b = bg / GG, g = bg - b * GG;
    const int tid = threadIdx.x;
    const float* src = qb + ((size_t)(b * CC_ + g * NGC_ + c)) * HWSZ;
#pragma unroll
    for (int e = tid; e < HWSZ; e += 256) img[e] = src[e];
    __syncthreads();
    const int oy = tid >> 4, ox = tid & 15;
    float s = dwb[c];
    const float* wf = dww + c * 25;
    const int iy0 = oy * 2 - 2, ix0 = ox * 2 - 2;
#pragma unroll
    for (int ky = 0; ky < 5; ++ky) {
        int iy = iy0 + ky;
        if (iy < 0 || iy > 31) continue;
#pragma unroll
        for (int kx = 0; kx < 5; ++kx) {
            int ix = ix0 + kx;
            if (ix < 0 || ix > 31) continue;
            s = fmaf(img[iy * 32 + ix], wf[ky * 5 + kx], s);
        }
    }
    cobuf[((size_t)(bg * 256 + tid)) * NGC_ + c] = s;   // [bg][pos][ch]
}

// ---------------- K2b: LN + GELU + pw + tanh, one wave per position ----------------
__global__ void offset_fin_kernel(const float* __restrict__ cobuf, const float* __restrict__ lng,
                                  const float* __restrict__ lnb, const float* __restrict__ pww,
                                  float* __restrict__ posb)
{
    const int lane = threadIdx.x & 63;
    const int gpos = blockIdx.x * 4 + (threadIdx.x >> 6);   // 0..6143
    const int bg = gpos >> 8, pos = gpos & 255;
    const int oy = (pos >> 4), ox = pos & 15;

    float v = cobuf[(size_t)gpos * NGC_ + lane];
    float s1 = v, s2 = v * v;
#pragma unroll
    for (int off = 32; off >= 1; off >>= 1) {
        s1 += __shfl_xor(s1, off);
        s2 += __shfl_xor(s2, off);
    }
    float mu = s1 * (1.f / 64.f);
    float var = s2 * (1.f / 64.f) - mu * mu;
    float rstd = rsqrtf(var + 1e-5f);
    float t = (v - mu) * rstd * lng[lane] + lnb[lane];
    float gv = 0.5f * t * (1.f + erff(t * 0.70710678118654752f));
    float o0 = pww[lane] * gv;
    float o1 = pww[64 + lane] * gv;
#pragma unroll
    for (int off = 32; off >= 1; off >>= 1) {
        o0 += __shfl_xor(o0, off);
        o1 += __shfl_xor(o1, off);
    }
    if (lane == 0) {
        float py = tanhf(o0) * (2.f / 15.f) + ((0.5f + (float)oy) * (1.f / 15.f)) * 2.f - 1.f;
        float px = tanhf(o1) * (2.f / 15.f) + ((0.5f + (float)ox) * (1.f / 15.f)) * 2.f - 1.f;
        posb[bg * 512 + pos * 2 + 0] = py;
        posb[bg * 512 + pos * 2 + 1] = px;
    }
}

// ---------------- K3: bilinear KV sampling ----------------
__global__ void sample_xs_kernel(const float* __restrict__ x, const float* __restrict__ posb,
                                 float* __restrict__ xsb)
{
    const int cc = blockIdx.x, bg = blockIdx.y;
    const int b = bg / GG, g = bg - b * GG;
    const int s = threadIdx.x;
    float py = posb[bg * 512 + s * 2 + 0];
    float px = posb[bg * 512 + s * 2 + 1];
    float xi = (px + 1.f) * 0.5f * 31.f;
    float yi = (py + 1.f) * 0.5f * 31.f;
    float x0f = floorf(xi), y0f = floorf(yi);
    int x0 = (int)x0f, y0 = (int)y0f;
    float wx1 = xi - x0f, wy1 = yi - y0f;
    const float* img = x + ((size_t)(b * CC_ + g * NGC_ + cc)) * HWSZ;
    float acc = 0.f;
#pragma unroll
    for (int t = 0; t < 4; ++t) {
        int iy = y0 + (t >> 1), ix = x0 + (t & 1);
        float w = ((t >> 1) ? wy1 : 1.f - wy1) * ((t & 1) ? wx1 : 1.f - wx1);
        if (iy >= 0 && iy <= 31 && ix >= 0 && ix <= 31)
            acc = fmaf(img[iy * 32 + ix], w, acc);
    }
    xsb[((size_t)(b * CC_ + g * NGC_ + cc)) * NS_ + s] = acc;
}

// ---------------- K5: fused attention, no-max softmax + masked-weight bias ----------------
// grid: (16 qtiles, 48 bh), block 512 = 64 queries(lanes) x 8 sample-groups(waves).
__launch_bounds__(512)
__global__ void attn_kernel(const float* __restrict__ qb, const float* __restrict__ kt,
                            const float* __restrict__ vt, const float* __restrict__ posb,
                            const float* __restrict__ rpe, float* __restrict__ ao)
{
    __shared__ float rp[4096];   // rpe (3969); reused: l[512] at 0, red float4[512] at +2048
    __shared__ float ps[512];
    const int bh = blockIdx.y;
    const int b = bh / NHD, h = bh - b * NHD;
    const int bg = b * GG + (h >> 1);
    const int tid = threadIdx.x;

    for (int e = tid; e < RPEW * RPEW; e += 512) rp[e] = rpe[(size_t)h * (RPEW * RPEW) + e];
    if (tid < 512) ps[tid] = posb[bg * 512 + tid];
    __syncthreads();

    const int q = tid & 63;
    const int sgrp = tid >> 6;
    const int qidx = blockIdx.x * 64 + q;
    const int row = qidx >> 5, col = qidx & 31;
    const float gyq = (float)row * (2.f / 31.f) - 1.f;
    const float gxq = (float)col * (2.f / 31.f) - 1.f;

    float qf[32];
    const float* qg = qb + ((size_t)(b * CC_ + h * HCH)) * HWSZ + qidx;
#pragma unroll
    for (int c = 0; c < 32; ++c) qf[c] = qg[(size_t)c * HWSZ];

    float l = 0.f;
    float oacc[32];
#pragma unroll
    for (int c = 0; c < 32; ++c) oacc[c] = 0.f;

    const float* kb2 = kt + ((size_t)bh * NS_) * 32;
    const float* vb2 = vt + ((size_t)bh * NS_) * 32;

    const int s0 = sgrp * 32;
#pragma unroll 2
    for (int s = s0; s < s0 + 32; ++s) {
        const float* kr = kb2 + s * 32;
        float d0 = 0.f, d1 = 0.f, d2 = 0.f, d3 = 0.f;
#pragma unroll
        for (int c8 = 0; c8 < 4; ++c8) {
            const int o = c8 * 8;
            float k0 = kr[o + 0], k1 = kr[o + 1], k2 = kr[o + 2], k3 = kr[o + 3];
            float k4 = kr[o + 4], k5 = kr[o + 5], k6 = kr[o + 6], k7 = kr[o + 7];
            d0 = fmaf(qf[o + 0], k0, d0); d1 = fmaf(qf[o + 1], k1, d1);
            d2 = fmaf(qf[o + 2], k2, d2); d3 = fmaf(qf[o + 3], k3, d3);
            d0 = fmaf(qf[o + 4], k4, d0); d1 = fmaf(qf[o + 5], k5, d1);
            d2 = fmaf(qf[o + 6], k6, d2); d3 = fmaf(qf[o + 7], k7, d3);
        }
        float dot = (d0 + d1) + (d2 + d3);

        float2 pp = *(const float2*)(ps + (s << 1));   // (py, px)
        float dy = (gyq - pp.x) * 0.5f, dx = (gxq - pp.y) * 0.5f;
        float yi = (dy + 1.f) * 31.f,  xi = (dx + 1.f) * 31.f;
        float y0f = floorf(yi), x0f = floorf(xi);
        int iy = (int)y0f, ix = (int)x0f;
        float wy1 = yi - y0f, wx1 = xi - x0f;
        float wy0 = 1.f - wy1, wx0 = 1.f - wx1;
        if ((unsigned)iy > 62u)       wy0 = 0.f;
        if ((unsigned)(iy + 1) > 62u) wy1 = 0.f;
        if ((unsigned)ix > 62u)       wx0 = 0.f;
        if ((unsigned)(ix + 1) > 62u) wx1 = 0.f;
        int ry0 = min(max(iy, 0), 62) * 63;
        int ry1 = min(max(iy + 1, 0), 62) * 63;
        int cx0 = min(max(ix, 0), 62);
        int cx1 = min(max(ix + 1, 0), 62);
        float t00 = rp[ry0 + cx0], t01 = rp[ry0 + cx1];
        float t10 = rp[ry1 + cx0], t11 = rp[ry1 + cx1];
        float bias = wy0 * fmaf(wx0, t00, wx1 * t01)
                   + wy1 * fmaf(wx0, t10, wx1 * t11);

        // logits are structurally small (|dot*SCALE|<~2, |bias|<~0.2): exp without max
        float p = __expf(fmaf(dot, SCALE_, bias));
        l += p;

        const float* vr = vb2 + s * 32;
#pragma unroll
        for (int c8 = 0; c8 < 4; ++c8) {
            const int o = c8 * 8;
            float v0 = vr[o + 0], v1 = vr[o + 1], v2 = vr[o + 2], v3 = vr[o + 3];
            float v4 = vr[o + 4], v5 = vr[o + 5], v6 = vr[o + 6], v7 = vr[o + 7];
            oacc[o + 0] = fmaf(p, v0, oacc[o + 0]); oacc[o + 1] = fmaf(p, v1, oacc[o + 1]);
            oacc[o + 2] = fmaf(p, v2, oacc[o + 2]); oacc[o + 3] = fmaf(p, v3, oacc[o + 3]);
            oacc[o + 4] = fmaf(p, v4, oacc[o + 4]); oacc[o + 5] = fmaf(p, v5, oacc[o + 5]);
            oacc[o + 6] = fmaf(p, v6, oacc[o + 6]); oacc[o + 7] = fmaf(p, v7, oacc[o + 7]);
        }
    }

    // ---- merge 8 sample-group waves: plain sums (no max tracking) ----
    __syncthreads();
    float* lbuf = rp;
    lbuf[tid] = l;
    __syncthreads();
    float L = 0.f;
#pragma unroll
    for (int j = 0; j < 8; ++j) L += lbuf[q + 64 * j];
    float scale = 1.f / L;

    float4* red = (float4*)(rp + 2048);
    float* og = ao + ((size_t)(b * CC_ + h * HCH)) * HWSZ + qidx;
#pragma unroll
    for (int cb = 0; cb < 8; ++cb) {
        __syncthreads();
        red[tid] = make_float4(oacc[cb * 4 + 0] * scale, oacc[cb * 4 + 1] * scale,
                               oacc[cb * 4 + 2] * scale, oacc[cb * 4 + 3] * scale);
        __syncthreads();
        if (sgrp == 0) {
            float4 sm = red[q];
#pragma unroll
            for (int j = 1; j < 8; ++j) {
                float4 a = red[q + 64 * j];
                sm.x += a.x; sm.y += a.y; sm.z += a.z; sm.w += a.w;
            }
            og[(size_t)(cb * 4 + 0) * HWSZ] = sm.x;
            og[(size_t)(cb * 4 + 1) * HWSZ] = sm.y;
            og[(size_t)(cb * 4 + 2) * HWSZ] = sm.z;
            og[(size_t)(cb * 4 + 3) * HWSZ] = sm.w;
        }
    }
}

extern "C" void kernel_launch(void* const* d_in, const int* in_sizes, int n_in,
                              void* d_out, int out_size, void* d_ws, size_t ws_size,
                              hipStream_t stream) {
    (void)in_sizes; (void)n_in; (void)out_size; (void)ws_size;
    const float* x   = (const float*)d_in[0];
    const float* Wq  = (const float*)d_in[1];
    const float* bq  = (const float*)d_in[2];
    const float* Wk  = (const float*)d_in[3];
    const float* bk  = (const float*)d_in[4];
    const float* Wv  = (const float*)d_in[5];
    const float* bv  = (const float*)d_in[6];
    const float* Wo  = (const float*)d_in[7];
    const float* bo  = (const float*)d_in[8];
    const float* dww = (const float*)d_in[9];
    const float* dwb = (const float*)d_in[10];
    const float* lng = (const float*)d_in[11];
    const float* lnb = (const float*)d_in[12];
    const float* pww = (const float*)d_in[13];
    const float* rpe = (const float*)d_in[14];
    float* out = (float*)d_out;

    float* ws   = (float*)d_ws;
    float* qbuf = ws;                       // 1572864
    float* posb = qbuf + 1572864;           // 12288
    float* xsb  = posb + 12288;             // 393216
    float* ktb  = xsb + 393216;             // 393216 [bh][s][32]
    float* vtb  = ktb + 393216;             // 393216 [bh][s][32]
    float* aout = vtb + 393216;             // 1572864
    float* cobuf = aout;                    // 393216, dead before attn writes aout

    conv1x1_k8<CC_><<<dim3(1, CC_ / 8, BB), 256, 0, stream>>>(Wq, bq, x, qbuf, HWSZ, CC_);
    offset_dw_kernel<<<dim3(NGC_, 24), 256, 0, stream>>>(qbuf, dww, dwb, cobuf);
    offset_fin_kernel<<<dim3(1536), 256, 0, stream>>>(cobuf, lng, lnb, pww, posb);
    sample_xs_kernel<<<dim3(NGC_, 24), 256, 0, stream>>>(x, posb, xsb);
    convkv_kernel<CC_><<<dim3(1, CC_ / 4, BB), 64, 0, stream>>>(Wk, bk, Wv, bv, xsb, ktb, vtb, NS_);
    attn_kernel<<<dim3(16, BB * NHD), 512, 0, stream>>>(qbuf, ktb, vtb, posb, rpe, aout);
    conv1x1_k8<CC_><<<dim3(1, CC_ / 8, BB), 256, 0, stream>>>(Wo, bo, aout, out, HWSZ, CC_);
}

// Round 8
// 208.139 us; speedup vs baseline: 1.5420x; 1.5420x over previous
//
#include <hip/hip_runtime.h>
#include <hip/hip_bf16.h>

#define BB 4
#define CC_ 384
#define HH 32
#define WW 32
#define HWSZ 1024
#define NHD 12
#define HCH 32
#define GG 6
#define NGC_ 64
#define GHD 2
#define HK_ 16
#define WK_ 16
#define NS_ 256
#define RPEW 63
#define SCALE_ 0.17677669529663687f

// ---------------- K1/K6: 1x1 conv / batched GEMM (standard layout) ----------------
template<int CIN>
__global__ void conv1x1_kernel(const float* __restrict__ W, const float* __restrict__ bias,
                               const float* __restrict__ X, float* __restrict__ Y,
                               int N, int OC)
{
    const int otile = blockIdx.y * 4;
    const int b = blockIdx.z;
    const int n4 = (blockIdx.x * blockDim.x + threadIdx.x) * 4;
    const float* Xb = X + (size_t)b * CIN * N + n4;
    const float* Wr = W + (size_t)otile * CIN;

    float acc[4][4];
#pragma unroll
    for (int j = 0; j < 4; ++j)
#pragma unroll
        for (int i = 0; i < 4; ++i) acc[j][i] = 0.f;

    for (int c = 0; c < CIN; ++c) {
        float4 xv = *(const float4*)(Xb + (size_t)c * N);
#pragma unroll
        for (int j = 0; j < 4; ++j) {
            float w = Wr[j * CIN + c];
            acc[j][0] = fmaf(w, xv.x, acc[j][0]);
            acc[j][1] = fmaf(w, xv.y, acc[j][1]);
            acc[j][2] = fmaf(w, xv.z, acc[j][2]);
            acc[j][3] = fmaf(w, xv.w, acc[j][3]);
        }
    }
#pragma unroll
    for (int j = 0; j < 4; ++j) {
        int o = otile + j;
        float bv = bias[o];
        float4 r = make_float4(acc[j][0] + bv, acc[j][1] + bv, acc[j][2] + bv, acc[j][3] + bv);
        *(float4*)(Y + ((size_t)(b * OC + o)) * N + n4) = r;
    }
}

// ---------------- K4: 1x1 conv with head-transposed output [bh][n][32] ----------------
template<int CIN>
__global__ void conv1x1t_kernel(const float* __restrict__ W, const float* __restrict__ bias,
                                const float* __restrict__ X, float* __restrict__ Y,
                                int N, int OC)
{
    const int otile = blockIdx.y * 4;          // 4-aligned => same head
    const int b = blockIdx.z;
    const int n4 = (blockIdx.x * blockDim.x + threadIdx.x) * 4;
    const float* Xb = X + (size_t)b * CIN * N + n4;
    const float* Wr = W + (size_t)otile * CIN;

    float acc[4][4];
#pragma unroll
    for (int j = 0; j < 4; ++j)
#pragma unroll
        for (int i = 0; i < 4; ++i) acc[j][i] = 0.f;

    for (int c = 0; c < CIN; ++c) {
        float4 xv = *(const float4*)(Xb + (size_t)c * N);
#pragma unroll
        for (int j = 0; j < 4; ++j) {
            float w = Wr[j * CIN + c];
            acc[j][0] = fmaf(w, xv.x, acc[j][0]);
            acc[j][1] = fmaf(w, xv.y, acc[j][1]);
            acc[j][2] = fmaf(w, xv.z, acc[j][2]);
            acc[j][3] = fmaf(w, xv.w, acc[j][3]);
        }
    }
    const int h = otile >> 5, cc = otile & 31;
    float bv0 = bias[otile + 0], bv1 = bias[otile + 1], bv2 = bias[otile + 2], bv3 = bias[otile + 3];
    float* outp = Y + ((size_t)(b * NHD + h) * N) * 32 + cc;
#pragma unroll
    for (int i = 0; i < 4; ++i) {
        float4 r = make_float4(acc[0][i] + bv0, acc[1][i] + bv1, acc[2][i] + bv2, acc[3][i] + bv3);
        *(float4*)(outp + (size_t)(n4 + i) * 32) = r;
    }
}

// ---------------- K2a: depthwise conv 5x5 stride 2, transposed output [bg][pos][ch] ----------------
__global__ void offset_dw_kernel(const float* __restrict__ qb, const float* __restrict__ dww,
                                 const float* __restrict__ dwb, float* __restrict__ cobuf)
{
    __shared__ float img[HWSZ];
    const int c = blockIdx.x, bg = blockIdx.y;
    const int b = bg / GG, g = bg - b * GG;
    const int tid = threadIdx.x;
    const float* src = qb + ((size_t)(b * CC_ + g * NGC_ + c)) * HWSZ;
#pragma unroll
    for (int e = tid; e < HWSZ; e += 256) img[e] = src[e];
    __syncthreads();
    const int oy = tid >> 4, ox = tid & 15;
    float s = dwb[c];
    const float* wf = dww + c * 25;
    const int iy0 = oy * 2 - 2, ix0 = ox * 2 - 2;
#pragma unroll
    for (int ky = 0; ky < 5; ++ky) {
        int iy = iy0 + ky;
        if (iy < 0 || iy > 31) continue;
#pragma unroll
        for (int kx = 0; kx < 5; ++kx) {
            int ix = ix0 + kx;
            if (ix < 0 || ix > 31) continue;
            s = fmaf(img[iy * 32 + ix], wf[ky * 5 + kx], s);
        }
    }
    cobuf[((size_t)(bg * 256 + tid)) * NGC_ + c] = s;   // [bg][pos][ch]
}

// ---------------- K2b: LN + GELU + pw + tanh, one wave per position ----------------
__global__ void offset_fin_kernel(const float* __restrict__ cobuf, const float* __restrict__ lng,
                                  const float* __restrict__ lnb, const float* __restrict__ pww,
                                  float* __restrict__ posb)
{
    const int lane = threadIdx.x & 63;
    const int gpos = blockIdx.x * 4 + (threadIdx.x >> 6);   // 0..6143
    const int bg = gpos >> 8, pos = gpos & 255;
    const int oy = (pos >> 4), ox = pos & 15;

    float v = cobuf[(size_t)gpos * NGC_ + lane];
    float s1 = v, s2 = v * v;
#pragma unroll
    for (int off = 32; off >= 1; off >>= 1) {
        s1 += __shfl_xor(s1, off);
        s2 += __shfl_xor(s2, off);
    }
    float mu = s1 * (1.f / 64.f);
    float var = s2 * (1.f / 64.f) - mu * mu;
    float rstd = rsqrtf(var + 1e-5f);
    float t = (v - mu) * rstd * lng[lane] + lnb[lane];
    float gv = 0.5f * t * (1.f + erff(t * 0.70710678118654752f));
    float o0 = pww[lane] * gv;
    float o1 = pww[64 + lane] * gv;
#pragma unroll
    for (int off = 32; off >= 1; off >>= 1) {
        o0 += __shfl_xor(o0, off);
        o1 += __shfl_xor(o1, off);
    }
    if (lane == 0) {
        float py = tanhf(o0) * (2.f / 15.f) + ((0.5f + (float)oy) * (1.f / 15.f)) * 2.f - 1.f;
        float px = tanhf(o1) * (2.f / 15.f) + ((0.5f + (float)ox) * (1.f / 15.f)) * 2.f - 1.f;
        posb[bg * 512 + pos * 2 + 0] = py;
        posb[bg * 512 + pos * 2 + 1] = px;
    }
}

// ---------------- K3: bilinear KV sampling ----------------
__global__ void sample_xs_kernel(const float* __restrict__ x, const float* __restrict__ posb,
                                 float* __restrict__ xsb)
{
    const int cc = blockIdx.x, bg = blockIdx.y;
    const int b = bg / GG, g = bg - b * GG;
    const int s = threadIdx.x;
    float py = posb[bg * 512 + s * 2 + 0];
    float px = posb[bg * 512 + s * 2 + 1];
    float xi = (px + 1.f) * 0.5f * 31.f;
    float yi = (py + 1.f) * 0.5f * 31.f;
    float x0f = floorf(xi), y0f = floorf(yi);
    int x0 = (int)x0f, y0 = (int)y0f;
    float wx1 = xi - x0f, wy1 = yi - y0f;
    const float* img = x + ((size_t)(b * CC_ + g * NGC_ + cc)) * HWSZ;
    float acc = 0.f;
#pragma unroll
    for (int t = 0; t < 4; ++t) {
        int iy = y0 + (t >> 1), ix = x0 + (t & 1);
        float w = ((t >> 1) ? wy1 : 1.f - wy1) * ((t & 1) ? wx1 : 1.f - wx1);
        if (iy >= 0 && iy <= 31 && ix >= 0 && ix <= 31)
            acc = fmaf(img[iy * 32 + ix], w, acc);
    }
    xsb[((size_t)(b * CC_ + g * NGC_ + cc)) * NS_ + s] = acc;
}

// ---------------- K5: fused attention, scalar K/V (readfirstlane), no-max softmax ----------------
// grid: (16 qtiles, 48 bh), block 512 = 64 queries(lanes) x 8 sample-groups(waves).
__launch_bounds__(512, 2)
__global__ void attn_kernel(const float* __restrict__ qb, const float* __restrict__ kt,
                            const float* __restrict__ vt, const float* __restrict__ posb,
                            const float* __restrict__ rpe, float* __restrict__ ao)
{
    __shared__ float rp[4096];   // rpe (3969); reused: l[512] at 0, red float4[512] at +2048
    __shared__ float ps[512];
    const int bh = blockIdx.y;
    const int b = bh / NHD, h = bh - b * NHD;
    const int bg = b * GG + (h >> 1);
    const int tid = threadIdx.x;

    for (int e = tid; e < RPEW * RPEW; e += 512) rp[e] = rpe[(size_t)h * (RPEW * RPEW) + e];
    if (tid < 512) ps[tid] = posb[bg * 512 + tid];
    __syncthreads();

    const int q = tid & 63;
    const int sgrp = __builtin_amdgcn_readfirstlane(tid >> 6);  // wave-uniform -> scalar K/V loads
    const int qidx = blockIdx.x * 64 + q;
    const int row = qidx >> 5, col = qidx & 31;
    const float gyq = (float)row * (2.f / 31.f) - 1.f;
    const float gxq = (float)col * (2.f / 31.f) - 1.f;

    float qf[32];
    const float* qg = qb + ((size_t)(b * CC_ + h * HCH)) * HWSZ + qidx;
#pragma unroll
    for (int c = 0; c < 32; ++c) qf[c] = qg[(size_t)c * HWSZ];

    float l = 0.f;
    float oacc[32];
#pragma unroll
    for (int c = 0; c < 32; ++c) oacc[c] = 0.f;

    const float* kb2 = kt + ((size_t)bh * NS_) * 32;
    const float* vb2 = vt + ((size_t)bh * NS_) * 32;

    const int s0 = sgrp * 32;
#pragma unroll 2
    for (int s = s0; s < s0 + 32; ++s) {
        const float* kr = kb2 + s * 32;   // wave-uniform -> s_load
        float d0 = 0.f, d1 = 0.f, d2 = 0.f, d3 = 0.f;
#pragma unroll
        for (int c8 = 0; c8 < 4; ++c8) {
            const int o = c8 * 8;
            float k0 = kr[o + 0], k1 = kr[o + 1], k2 = kr[o + 2], k3 = kr[o + 3];
            float k4 = kr[o + 4], k5 = kr[o + 5], k6 = kr[o + 6], k7 = kr[o + 7];
            d0 = fmaf(qf[o + 0], k0, d0); d1 = fmaf(qf[o + 1], k1, d1);
            d2 = fmaf(qf[o + 2], k2, d2); d3 = fmaf(qf[o + 3], k3, d3);
            d0 = fmaf(qf[o + 4], k4, d0); d1 = fmaf(qf[o + 5], k5, d1);
            d2 = fmaf(qf[o + 6], k6, d2); d3 = fmaf(qf[o + 7], k7, d3);
        }
        float dot = (d0 + d1) + (d2 + d3);

        float2 pp = *(const float2*)(ps + (s << 1));   // (py, px)
        float dy = (gyq - pp.x) * 0.5f, dx = (gxq - pp.y) * 0.5f;
        float yi = (dy + 1.f) * 31.f,  xi = (dx + 1.f) * 31.f;
        float y0f = floorf(yi), x0f = floorf(xi);
        int iy = (int)y0f, ix = (int)x0f;
        float wy1 = yi - y0f, wx1 = xi - x0f;
        float wy0 = 1.f - wy1, wx0 = 1.f - wx1;
        if ((unsigned)iy > 62u)       wy0 = 0.f;
        if ((unsigned)(iy + 1) > 62u) wy1 = 0.f;
        if ((unsigned)ix > 62u)       wx0 = 0.f;
        if ((unsigned)(ix + 1) > 62u) wx1 = 0.f;
        int ry0 = min(max(iy, 0), 62) * 63;
        int ry1 = min(max(iy + 1, 0), 62) * 63;
        int cx0 = min(max(ix, 0), 62);
        int cx1 = min(max(ix + 1, 0), 62);
        float t00 = rp[ry0 + cx0], t01 = rp[ry0 + cx1];
        float t10 = rp[ry1 + cx0], t11 = rp[ry1 + cx1];
        float bias = wy0 * fmaf(wx0, t00, wx1 * t01)
                   + wy1 * fmaf(wx0, t10, wx1 * t11);

        // logits structurally small (|dot*SCALE| small, |bias| small): exp without max tracking
        float p = __expf(fmaf(dot, SCALE_, bias));
        l += p;

        const float* vr = vb2 + s * 32;   // wave-uniform -> s_load
#pragma unroll
        for (int c8 = 0; c8 < 4; ++c8) {
            const int o = c8 * 8;
            float v0 = vr[o + 0], v1 = vr[o + 1], v2 = vr[o + 2], v3 = vr[o + 3];
            float v4 = vr[o + 4], v5 = vr[o + 5], v6 = vr[o + 6], v7 = vr[o + 7];
            oacc[o + 0] = fmaf(p, v0, oacc[o + 0]); oacc[o + 1] = fmaf(p, v1, oacc[o + 1]);
            oacc[o + 2] = fmaf(p, v2, oacc[o + 2]); oacc[o + 3] = fmaf(p, v3, oacc[o + 3]);
            oacc[o + 4] = fmaf(p, v4, oacc[o + 4]); oacc[o + 5] = fmaf(p, v5, oacc[o + 5]);
            oacc[o + 6] = fmaf(p, v6, oacc[o + 6]); oacc[o + 7] = fmaf(p, v7, oacc[o + 7]);
        }
    }

    // ---- merge 8 sample-group waves: plain sums ----
    __syncthreads();
    float* lbuf = rp;
    lbuf[tid] = l;
    __syncthreads();
    float L = 0.f;
#pragma unroll
    for (int j = 0; j < 8; ++j) L += lbuf[q + 64 * j];
    float scale = 1.f / L;

    float4* red = (float4*)(rp + 2048);
    float* og = ao + ((size_t)(b * CC_ + h * HCH)) * HWSZ + qidx;
#pragma unroll
    for (int cb = 0; cb < 8; ++cb) {
        __syncthreads();
        red[tid] = make_float4(oacc[cb * 4 + 0] * scale, oacc[cb * 4 + 1] * scale,
                               oacc[cb * 4 + 2] * scale, oacc[cb * 4 + 3] * scale);
        __syncthreads();
        if (sgrp == 0) {
            float4 sm = red[q];
#pragma unroll
            for (int j = 1; j < 8; ++j) {
                float4 a = red[q + 64 * j];
                sm.x += a.x; sm.y += a.y; sm.z += a.z; sm.w += a.w;
            }
            og[(size_t)(cb * 4 + 0) * HWSZ] = sm.x;
            og[(size_t)(cb * 4 + 1) * HWSZ] = sm.y;
            og[(size_t)(cb * 4 + 2) * HWSZ] = sm.z;
            og[(size_t)(cb * 4 + 3) * HWSZ] = sm.w;
        }
    }
}

extern "C" void kernel_launch(void* const* d_in, const int* in_sizes, int n_in,
                              void* d_out, int out_size, void* d_ws, size_t ws_size,
                              hipStream_t stream) {
    (void)in_sizes; (void)n_in; (void)out_size; (void)ws_size;
    const float* x   = (const float*)d_in[0];
    const float* Wq  = (const float*)d_in[1];
    const float* bq  = (const float*)d_in[2];
    const float* Wk  = (const float*)d_in[3];
    const float* bk  = (const float*)d_in[4];
    const float* Wv  = (const float*)d_in[5];
    const float* bv  = (const float*)d_in[6];
    const float* Wo  = (const float*)d_in[7];
    const float* bo  = (const float*)d_in[8];
    const float* dww = (const float*)d_in[9];
    const float* dwb = (const float*)d_in[10];
    const float* lng = (const float*)d_in[11];
    const float* lnb = (const float*)d_in[12];
    const float* pww = (const float*)d_in[13];
    const float* rpe = (const float*)d_in[14];
    float* out = (float*)d_out;

    float* ws   = (float*)d_ws;
    float* qbuf = ws;                       // 1572864
    float* posb = qbuf + 1572864;           // 12288
    float* xsb  = posb + 12288;             // 393216
    float* ktb  = xsb + 393216;             // 393216 [bh][s][32]
    float* vtb  = ktb + 393216;             // 393216 [bh][s][32]
    float* aout = vtb + 393216;             // 1572864
    float* cobuf = aout;                    // 393216, dead before attn writes aout

    conv1x1_kernel<CC_><<<dim3(1, CC_ / 4, BB), 256, 0, stream>>>(Wq, bq, x, qbuf, HWSZ, CC_);
    offset_dw_kernel<<<dim3(NGC_, 24), 256, 0, stream>>>(qbuf, dww, dwb, cobuf);
    offset_fin_kernel<<<dim3(1536), 256, 0, stream>>>(cobuf, lng, lnb, pww, posb);
    sample_xs_kernel<<<dim3(NGC_, 24), 256, 0, stream>>>(x, posb, xsb);
    conv1x1t_kernel<CC_><<<dim3(1, CC_ / 4, BB), 64, 0, stream>>>(Wk, bk, xsb, ktb, NS_, CC_);
    conv1x1t_kernel<CC_><<<dim3(1, CC_ / 4, BB), 64, 0, stream>>>(Wv, bv, xsb, vtb, NS_, CC_);
    attn_kernel<<<dim3(16, BB * NHD), 512, 0, stream>>>(qbuf, ktb, vtb, posb, rpe, aout);
    conv1x1_kernel<CC_><<<dim3(1, CC_ / 4, BB), 256, 0, stream>>>(Wo, bo, aout, out, HWSZ, CC_);
}

// Round 9
// 176.127 us; speedup vs baseline: 1.8223x; 1.1818x over previous
//
#include <hip/hip_runtime.h>
#include <hip/hip_bf16.h>
#include <hip/hip_fp16.h>

#define BB 4
#define CC_ 384
#define HH 32
#define WW 32
#define HWSZ 1024
#define NHD 12
#define HCH 32
#define GG 6
#define NGC_ 64
#define GHD 2
#define HK_ 16
#define WK_ 16
#define NS_ 256
#define RPEW 63
#define SCALE_ 0.17677669529663687f

// ---------------- K1/K6: 1x1 conv, column-split (thread = 1 column) ----------------
// grid: (N/256, OC/4, B), block 256. Scalar dword loads, 4 outputs/thread.
template<int CIN>
__global__ void conv1x1_cs(const float* __restrict__ W, const float* __restrict__ bias,
                           const float* __restrict__ X, float* __restrict__ Y,
                           int N, int OC)
{
    const int otile = blockIdx.y * 4;
    const int b = blockIdx.z;
    const int n = blockIdx.x * 256 + threadIdx.x;
    const float* Xb = X + (size_t)b * CIN * N + n;
    const float* Wr = W + (size_t)otile * CIN;

    float a0 = 0.f, a1 = 0.f, a2 = 0.f, a3 = 0.f;
#pragma unroll 4
    for (int c = 0; c < CIN; ++c) {
        float xv = Xb[(size_t)c * N];
        a0 = fmaf(Wr[c], xv, a0);
        a1 = fmaf(Wr[CIN + c], xv, a1);
        a2 = fmaf(Wr[2 * CIN + c], xv, a2);
        a3 = fmaf(Wr[3 * CIN + c], xv, a3);
    }
    float* Yb = Y + ((size_t)(b * OC + otile)) * N + n;
    Yb[0]            = a0 + bias[otile + 0];
    Yb[N]            = a1 + bias[otile + 1];
    Yb[2 * (size_t)N] = a2 + bias[otile + 2];
    Yb[3 * (size_t)N] = a3 + bias[otile + 3];
}

// ---------------- K4: fused K+V 1x1 conv, head-transposed outputs [bh][n][32] ----------------
// grid: (OC/4, B), block 256 = one thread per sample column.
template<int CIN>
__global__ void convkv_kernel(const float* __restrict__ Wk, const float* __restrict__ bk,
                              const float* __restrict__ Wv, const float* __restrict__ bv,
                              const float* __restrict__ X, float* __restrict__ Yk,
                              float* __restrict__ Yv, int N)
{
    const int otile = blockIdx.x * 4;          // 4-aligned => same head
    const int b = blockIdx.y;
    const int n = threadIdx.x;
    const float* Xb = X + (size_t)b * CIN * N + n;
    const float* Wkr = Wk + (size_t)otile * CIN;
    const float* Wvr = Wv + (size_t)otile * CIN;

    float ak0 = 0.f, ak1 = 0.f, ak2 = 0.f, ak3 = 0.f;
    float av0 = 0.f, av1 = 0.f, av2 = 0.f, av3 = 0.f;
#pragma unroll 4
    for (int c = 0; c < CIN; ++c) {
        float xv = Xb[(size_t)c * N];
        ak0 = fmaf(Wkr[c], xv, ak0);
        ak1 = fmaf(Wkr[CIN + c], xv, ak1);
        ak2 = fmaf(Wkr[2 * CIN + c], xv, ak2);
        ak3 = fmaf(Wkr[3 * CIN + c], xv, ak3);
        av0 = fmaf(Wvr[c], xv, av0);
        av1 = fmaf(Wvr[CIN + c], xv, av1);
        av2 = fmaf(Wvr[2 * CIN + c], xv, av2);
        av3 = fmaf(Wvr[3 * CIN + c], xv, av3);
    }
    const int h = otile >> 5, cc = otile & 31;
    const size_t obase = (((size_t)(b * NHD + h) * N) + n) * 32 + cc;
    *(float4*)(Yk + obase) = make_float4(ak0 + bk[otile + 0], ak1 + bk[otile + 1],
                                         ak2 + bk[otile + 2], ak3 + bk[otile + 3]);
    *(float4*)(Yv + obase) = make_float4(av0 + bv[otile + 0], av1 + bv[otile + 1],
                                         av2 + bv[otile + 2], av3 + bv[otile + 3]);
}

// ---------------- K2a: depthwise conv 5x5 stride 2, transposed output [bg][pos][ch] ----------------
__global__ void offset_dw_kernel(const float* __restrict__ qb, const float* __restrict__ dww,
                                 const float* __restrict__ dwb, float* __restrict__ cobuf)
{
    __shared__ float img[HWSZ];
    const int c = blockIdx.x, bg = blockIdx.y;
    const int b = bg / GG, g = bg - b * GG;
    const int tid = threadIdx.x;
    const float* src = qb + ((size_t)(b * CC_ + g * NGC_ + c)) * HWSZ;
#pragma unroll
    for (int e = tid; e < HWSZ; e += 256) img[e] = src[e];
    __syncthreads();
    const int oy = tid >> 4, ox = tid & 15;
    float s = dwb[c];
    const float* wf = dww + c * 25;
    const int iy0 = oy * 2 - 2, ix0 = ox * 2 - 2;
#pragma unroll
    for (int ky = 0; ky < 5; ++ky) {
        int iy = iy0 + ky;
        if (iy < 0 || iy > 31) continue;
#pragma unroll
        for (int kx = 0; kx < 5; ++kx) {
            int ix = ix0 + kx;
            if (ix < 0 || ix > 31) continue;
            s = fmaf(img[iy * 32 + ix], wf[ky * 5 + kx], s);
        }
    }
    cobuf[((size_t)(bg * 256 + tid)) * NGC_ + c] = s;   // [bg][pos][ch]
}

// ---------------- K2b: LN + GELU + pw + tanh, one wave per position ----------------
__global__ void offset_fin_kernel(const float* __restrict__ cobuf, const float* __restrict__ lng,
                                  const float* __restrict__ lnb, const float* __restrict__ pww,
                                  float* __restrict__ posb)
{
    const int lane = threadIdx.x & 63;
    const int gpos = blockIdx.x * 4 + (threadIdx.x >> 6);   // 0..6143
    const int bg = gpos >> 8, pos = gpos & 255;
    const int oy = (pos >> 4), ox = pos & 15;

    float v = cobuf[(size_t)gpos * NGC_ + lane];
    float s1 = v, s2 = v * v;
#pragma unroll
    for (int off = 32; off >= 1; off >>= 1) {
        s1 += __shfl_xor(s1, off);
        s2 += __shfl_xor(s2, off);
    }
    float mu = s1 * (1.f / 64.f);
    float var = s2 * (1.f / 64.f) - mu * mu;
    float rstd = rsqrtf(var + 1e-5f);
    float t = (v - mu) * rstd * lng[lane] + lnb[lane];
    float gv = 0.5f * t * (1.f + erff(t * 0.70710678118654752f));
    float o0 = pww[lane] * gv;
    float o1 = pww[64 + lane] * gv;
#pragma unroll
    for (int off = 32; off >= 1; off >>= 1) {
        o0 += __shfl_xor(o0, off);
        o1 += __shfl_xor(o1, off);
    }
    if (lane == 0) {
        float py = tanhf(o0) * (2.f / 15.f) + ((0.5f + (float)oy) * (1.f / 15.f)) * 2.f - 1.f;
        float px = tanhf(o1) * (2.f / 15.f) + ((0.5f + (float)ox) * (1.f / 15.f)) * 2.f - 1.f;
        posb[bg * 512 + pos * 2 + 0] = py;
        posb[bg * 512 + pos * 2 + 1] = px;
    }
}

// ---------------- K3: bilinear KV sampling ----------------
__global__ void sample_xs_kernel(const float* __restrict__ x, const float* __restrict__ posb,
                                 float* __restrict__ xsb)
{
    const int cc = blockIdx.x, bg = blockIdx.y;
    const int b = bg / GG, g = bg - b * GG;
    const int s = threadIdx.x;
    float py = posb[bg * 512 + s * 2 + 0];
    float px = posb[bg * 512 + s * 2 + 1];
    float xi = (px + 1.f) * 0.5f * 31.f;
    float yi = (py + 1.f) * 0.5f * 31.f;
    float x0f = floorf(xi), y0f = floorf(yi);
    int x0 = (int)x0f, y0 = (int)y0f;
    float wx1 = xi - x0f, wy1 = yi - y0f;
    const float* img = x + ((size_t)(b * CC_ + g * NGC_ + cc)) * HWSZ;
    float acc = 0.f;
#pragma unroll
    for (int t = 0; t < 4; ++t) {
        int iy = y0 + (t >> 1), ix = x0 + (t & 1);
        float w = ((t >> 1) ? wy1 : 1.f - wy1) * ((t & 1) ? wx1 : 1.f - wx1);
        if (iy >= 0 && iy <= 31 && ix >= 0 && ix <= 31)
            acc = fmaf(img[iy * 32 + ix], w, acc);
    }
    xsb[((size_t)(b * CC_ + g * NGC_ + cc)) * NS_ + s] = acc;
}

// ---------------- K5: fused attention, scalar K/V, fp16 rpe table (10 KB LDS) ----------------
// grid: (16 qtiles, 48 bh), block 512 = 64 queries(lanes) x 8 sample-groups(waves).
__launch_bounds__(512)
__global__ void attn_kernel(const float* __restrict__ qb, const float* __restrict__ kt,
                            const float* __restrict__ vt, const float* __restrict__ posb,
                            const float* __restrict__ rpe, float* __restrict__ ao)
{
    // union: phase 1 = rph (fp16 rpe, 8KB) + ps (2KB); phase 2 = lbuf[512] + red[512]f4
    __shared__ float smem[2560];
    __half* rph = (__half*)smem;          // 4096 halfs (3969 used)
    float* ps = smem + 2048;              // 512 floats
    const int bh = blockIdx.y;
    const int b = bh / NHD, h = bh - b * NHD;
    const int bg = b * GG + (h >> 1);
    const int tid = threadIdx.x;

    for (int e = tid; e < RPEW * RPEW; e += 512)
        rph[e] = __float2half(rpe[(size_t)h * (RPEW * RPEW) + e]);
    ps[tid] = posb[bg * 512 + tid];
    __syncthreads();

    const int q = tid & 63;
    const int sgrp = __builtin_amdgcn_readfirstlane(tid >> 6);  // wave-uniform -> scalar K/V loads
    const int qidx = blockIdx.x * 64 + q;
    const int row = qidx >> 5, col = qidx & 31;
    const float gyq = (float)row * (2.f / 31.f) - 1.f;
    const float gxq = (float)col * (2.f / 31.f) - 1.f;

    float qf[32];
    const float* qg = qb + ((size_t)(b * CC_ + h * HCH)) * HWSZ + qidx;
#pragma unroll
    for (int c = 0; c < 32; ++c) qf[c] = qg[(size_t)c * HWSZ];

    float l = 0.f;
    float oacc[32];
#pragma unroll
    for (int c = 0; c < 32; ++c) oacc[c] = 0.f;

    const float* kb2 = kt + ((size_t)bh * NS_) * 32;
    const float* vb2 = vt + ((size_t)bh * NS_) * 32;

    const int s0 = sgrp * 32;
#pragma unroll 2
    for (int s = s0; s < s0 + 32; ++s) {
        const float* kr = kb2 + s * 32;   // wave-uniform -> s_load
        float d0 = 0.f, d1 = 0.f, d2 = 0.f, d3 = 0.f;
#pragma unroll
        for (int c8 = 0; c8 < 4; ++c8) {
            const int o = c8 * 8;
            float k0 = kr[o + 0], k1 = kr[o + 1], k2 = kr[o + 2], k3 = kr[o + 3];
            float k4 = kr[o + 4], k5 = kr[o + 5], k6 = kr[o + 6], k7 = kr[o + 7];
            d0 = fmaf(qf[o + 0], k0, d0); d1 = fmaf(qf[o + 1], k1, d1);
            d2 = fmaf(qf[o + 2], k2, d2); d3 = fmaf(qf[o + 3], k3, d3);
            d0 = fmaf(qf[o + 4], k4, d0); d1 = fmaf(qf[o + 5], k5, d1);
            d2 = fmaf(qf[o + 6], k6, d2); d3 = fmaf(qf[o + 7], k7, d3);
        }
        float dot = (d0 + d1) + (d2 + d3);

        float2 pp = *(const float2*)(ps + (s << 1));   // (py, px)
        float dy = (gyq - pp.x) * 0.5f, dx = (gxq - pp.y) * 0.5f;
        float yi = (dy + 1.f) * 31.f,  xi = (dx + 1.f) * 31.f;
        float y0f = floorf(yi), x0f = floorf(xi);
        int iy = (int)y0f, ix = (int)x0f;
        float wy1 = yi - y0f, wx1 = xi - x0f;
        float wy0 = 1.f - wy1, wx0 = 1.f - wx1;
        if ((unsigned)iy > 62u)       wy0 = 0.f;
        if ((unsigned)(iy + 1) > 62u) wy1 = 0.f;
        if ((unsigned)ix > 62u)       wx0 = 0.f;
        if ((unsigned)(ix + 1) > 62u) wx1 = 0.f;
        int ry0 = min(max(iy, 0), 62) * 63;
        int ry1 = min(max(iy + 1, 0), 62) * 63;
        int cx0 = min(max(ix, 0), 62);
        int cx1 = min(max(ix + 1, 0), 62);
        float t00 = __half2float(rph[ry0 + cx0]), t01 = __half2float(rph[ry0 + cx1]);
        float t10 = __half2float(rph[ry1 + cx0]), t11 = __half2float(rph[ry1 + cx1]);
        float bias = wy0 * fmaf(wx0, t00, wx1 * t01)
                   + wy1 * fmaf(wx0, t10, wx1 * t11);

        // logits structurally small: exp without max tracking
        float p = __expf(fmaf(dot, SCALE_, bias));
        l += p;

        const float* vr = vb2 + s * 32;   // wave-uniform -> s_load
#pragma unroll
        for (int c8 = 0; c8 < 4; ++c8) {
            const int o = c8 * 8;
            float v0 = vr[o + 0], v1 = vr[o + 1], v2 = vr[o + 2], v3 = vr[o + 3];
            float v4 = vr[o + 4], v5 = vr[o + 5], v6 = vr[o + 6], v7 = vr[o + 7];
            oacc[o + 0] = fmaf(p, v0, oacc[o + 0]); oacc[o + 1] = fmaf(p, v1, oacc[o + 1]);
            oacc[o + 2] = fmaf(p, v2, oacc[o + 2]); oacc[o + 3] = fmaf(p, v3, oacc[o + 3]);
            oacc[o + 4] = fmaf(p, v4, oacc[o + 4]); oacc[o + 5] = fmaf(p, v5, oacc[o + 5]);
            oacc[o + 6] = fmaf(p, v6, oacc[o + 6]); oacc[o + 7] = fmaf(p, v7, oacc[o + 7]);
        }
    }

    // ---- merge 8 sample-group waves: plain sums (rph/ps dead now) ----
    __syncthreads();
    float* lbuf = smem;                    // 512 floats
    float4* red = (float4*)(smem + 512);   // 512 float4
    lbuf[tid] = l;
    __syncthreads();
    float L = 0.f;
#pragma unroll
    for (int j = 0; j < 8; ++j) L += lbuf[q + 64 * j];
    float scale = 1.f / L;

    float* og = ao + ((size_t)(b * CC_ + h * HCH)) * HWSZ + qidx;
#pragma unroll
    for (int cb = 0; cb < 8; ++cb) {
        __syncthreads();
        red[tid] = make_float4(oacc[cb * 4 + 0] * scale, oacc[cb * 4 + 1] * scale,
                               oacc[cb * 4 + 2] * scale, oacc[cb * 4 + 3] * scale);
        __syncthreads();
        if (sgrp == 0) {
            float4 sm = red[q];
#pragma unroll
            for (int j = 1; j < 8; ++j) {
                float4 a = red[q + 64 * j];
                sm.x += a.x; sm.y += a.y; sm.z += a.z; sm.w += a.w;
            }
            og[(size_t)(cb * 4 + 0) * HWSZ] = sm.x;
            og[(size_t)(cb * 4 + 1) * HWSZ] = sm.y;
            og[(size_t)(cb * 4 + 2) * HWSZ] = sm.z;
            og[(size_t)(cb * 4 + 3) * HWSZ] = sm.w;
        }
    }
}

extern "C" void kernel_launch(void* const* d_in, const int* in_sizes, int n_in,
                              void* d_out, int out_size, void* d_ws, size_t ws_size,
                              hipStream_t stream) {
    (void)in_sizes; (void)n_in; (void)out_size; (void)ws_size;
    const float* x   = (const float*)d_in[0];
    const float* Wq  = (const float*)d_in[1];
    const float* bq  = (const float*)d_in[2];
    const float* Wk  = (const float*)d_in[3];
    const float* bk  = (const float*)d_in[4];
    const float* Wv  = (const float*)d_in[5];
    const float* bv  = (const float*)d_in[6];
    const float* Wo  = (const float*)d_in[7];
    const float* bo  = (const float*)d_in[8];
    const float* dww = (const float*)d_in[9];
    const float* dwb = (const float*)d_in[10];
    const float* lng = (const float*)d_in[11];
    const float* lnb = (const float*)d_in[12];
    const float* pww = (const float*)d_in[13];
    const float* rpe = (const float*)d_in[14];
    float* out = (float*)d_out;

    float* ws   = (float*)d_ws;
    float* qbuf = ws;                       // 1572864
    float* posb = qbuf + 1572864;           // 12288
    float* xsb  = posb + 12288;             // 393216
    float* ktb  = xsb + 393216;             // 393216 [bh][s][32]
    float* vtb  = ktb + 393216;             // 393216 [bh][s][32]
    float* aout = vtb + 393216;             // 1572864
    float* cobuf = aout;                    // 393216, dead before attn writes aout

    conv1x1_cs<CC_><<<dim3(4, CC_ / 4, BB), 256, 0, stream>>>(Wq, bq, x, qbuf, HWSZ, CC_);
    offset_dw_kernel<<<dim3(NGC_, 24), 256, 0, stream>>>(qbuf, dww, dwb, cobuf);
    offset_fin_kernel<<<dim3(1536), 256, 0, stream>>>(cobuf, lng, lnb, pww, posb);
    sample_xs_kernel<<<dim3(NGC_, 24), 256, 0, stream>>>(x, posb, xsb);
    convkv_kernel<CC_><<<dim3(CC_ / 4, BB), 256, 0, stream>>>(Wk, bk, Wv, bv, xsb, ktb, vtb, NS_);
    attn_kernel<<<dim3(16, BB * NHD), 512, 0, stream>>>(qbuf, ktb, vtb, posb, rpe, aout);
    conv1x1_cs<CC_><<<dim3(4, CC_ / 4, BB), 256, 0, stream>>>(Wo, bo, aout, out, HWSZ, CC_);
}

// Round 10
// 171.247 us; speedup vs baseline: 1.8742x; 1.0285x over previous
//
#include <hip/hip_runtime.h>
#include <hip/hip_bf16.h>
#include <hip/hip_fp16.h>

#define BB 4
#define CC_ 384
#define HH 32
#define WW 32
#define HWSZ 1024
#define NHD 12
#define HCH 32
#define GG 6
#define NGC_ 64
#define GHD 2
#define HK_ 16
#define WK_ 16
#define NS_ 256
#define RPEW 63
#define SCALE_ 0.17677669529663687f

typedef _Float16 half2_t __attribute__((ext_vector_type(2)));

#if defined(__has_builtin)
#if __has_builtin(__builtin_amdgcn_fdot2)
#define HAS_FDOT2 1
#endif
#endif

// ---------------- K1/K6: 1x1 conv, column-split, 8 outputs/thread ----------------
// grid: (N/256, OC/8, B), block 256.
template<int CIN>
__global__ void conv1x1_cs8(const float* __restrict__ W, const float* __restrict__ bias,
                            const float* __restrict__ X, float* __restrict__ Y,
                            int N, int OC)
{
    const int otile = blockIdx.y * 8;
    const int b = blockIdx.z;
    const int n = blockIdx.x * 256 + threadIdx.x;
    const float* Xb = X + (size_t)b * CIN * N + n;
    const float* Wr = W + (size_t)otile * CIN;

    float a[8];
#pragma unroll
    for (int j = 0; j < 8; ++j) a[j] = 0.f;

#pragma unroll 4
    for (int c = 0; c < CIN; ++c) {
        float xv = Xb[(size_t)c * N];
#pragma unroll
        for (int j = 0; j < 8; ++j)
            a[j] = fmaf(Wr[j * CIN + c], xv, a[j]);
    }
    float* Yb = Y + ((size_t)(b * OC + otile)) * N + n;
#pragma unroll
    for (int j = 0; j < 8; ++j)
        Yb[(size_t)j * N] = a[j] + bias[otile + j];
}

// ---------------- K4: fused K+V 1x1 conv; K -> fp16 [bh][n][32], V -> fp32 [bh][n][32] ----------------
// grid: (OC/4, B), block 256 = one thread per sample column.
template<int CIN>
__global__ void convkv_kernel(const float* __restrict__ Wk, const float* __restrict__ bk,
                              const float* __restrict__ Wv, const float* __restrict__ bv,
                              const float* __restrict__ X, __half* __restrict__ Yk,
                              float* __restrict__ Yv, int N)
{
    const int otile = blockIdx.x * 4;          // 4-aligned => same head
    const int b = blockIdx.y;
    const int n = threadIdx.x;
    const float* Xb = X + (size_t)b * CIN * N + n;
    const float* Wkr = Wk + (size_t)otile * CIN;
    const float* Wvr = Wv + (size_t)otile * CIN;

    float ak0 = 0.f, ak1 = 0.f, ak2 = 0.f, ak3 = 0.f;
    float av0 = 0.f, av1 = 0.f, av2 = 0.f, av3 = 0.f;
#pragma unroll 4
    for (int c = 0; c < CIN; ++c) {
        float xv = Xb[(size_t)c * N];
        ak0 = fmaf(Wkr[c], xv, ak0);
        ak1 = fmaf(Wkr[CIN + c], xv, ak1);
        ak2 = fmaf(Wkr[2 * CIN + c], xv, ak2);
        ak3 = fmaf(Wkr[3 * CIN + c], xv, ak3);
        av0 = fmaf(Wvr[c], xv, av0);
        av1 = fmaf(Wvr[CIN + c], xv, av1);
        av2 = fmaf(Wvr[2 * CIN + c], xv, av2);
        av3 = fmaf(Wvr[3 * CIN + c], xv, av3);
    }
    const int h = otile >> 5, cc = otile & 31;
    const size_t obase = (((size_t)(b * NHD + h) * N) + n) * 32 + cc;
    __half2* yk2 = (__half2*)(Yk + obase);
    yk2[0] = __floats2half2_rn(ak0 + bk[otile + 0], ak1 + bk[otile + 1]);
    yk2[1] = __floats2half2_rn(ak2 + bk[otile + 2], ak3 + bk[otile + 3]);
    *(float4*)(Yv + obase) = make_float4(av0 + bv[otile + 0], av1 + bv[otile + 1],
                                         av2 + bv[otile + 2], av3 + bv[otile + 3]);
}

// ---------------- K2a: depthwise conv 5x5 stride 2, transposed output [bg][pos][ch] ----------------
__global__ void offset_dw_kernel(const float* __restrict__ qb, const float* __restrict__ dww,
                                 const float* __restrict__ dwb, float* __restrict__ cobuf)
{
    __shared__ float img[HWSZ];
    const int c = blockIdx.x, bg = blockIdx.y;
    const int b = bg / GG, g = bg - b * GG;
    const int tid = threadIdx.x;
    const float* src = qb + ((size_t)(b * CC_ + g * NGC_ + c)) * HWSZ;
#pragma unroll
    for (int e = tid; e < HWSZ; e += 256) img[e] = src[e];
    __syncthreads();
    const int oy = tid >> 4, ox = tid & 15;
    float s = dwb[c];
    const float* wf = dww + c * 25;
    const int iy0 = oy * 2 - 2, ix0 = ox * 2 - 2;
#pragma unroll
    for (int ky = 0; ky < 5; ++ky) {
        int iy = iy0 + ky;
        if (iy < 0 || iy > 31) continue;
#pragma unroll
        for (int kx = 0; kx < 5; ++kx) {
            int ix = ix0 + kx;
            if (ix < 0 || ix > 31) continue;
            s = fmaf(img[iy * 32 + ix], wf[ky * 5 + kx], s);
        }
    }
    cobuf[((size_t)(bg * 256 + tid)) * NGC_ + c] = s;   // [bg][pos][ch]
}

// ---------------- K2b: LN + GELU + pw + tanh, one wave per position ----------------
__global__ void offset_fin_kernel(const float* __restrict__ cobuf, const float* __restrict__ lng,
                                  const float* __restrict__ lnb, const float* __restrict__ pww,
                                  float* __restrict__ posb)
{
    const int lane = threadIdx.x & 63;
    const int gpos = blockIdx.x * 4 + (threadIdx.x >> 6);   // 0..6143
    const int bg = gpos >> 8, pos = gpos & 255;
    const int oy = (pos >> 4), ox = pos & 15;

    float v = cobuf[(size_t)gpos * NGC_ + lane];
    float s1 = v, s2 = v * v;
#pragma unroll
    for (int off = 32; off >= 1; off >>= 1) {
        s1 += __shfl_xor(s1, off);
        s2 += __shfl_xor(s2, off);
    }
    float mu = s1 * (1.f / 64.f);
    float var = s2 * (1.f / 64.f) - mu * mu;
    float rstd = rsqrtf(var + 1e-5f);
    float t = (v - mu) * rstd * lng[lane] + lnb[lane];
    float gv = 0.5f * t * (1.f + erff(t * 0.70710678118654752f));
    float o0 = pww[lane] * gv;
    float o1 = pww[64 + lane] * gv;
#pragma unroll
    for (int off = 32; off >= 1; off >>= 1) {
        o0 += __shfl_xor(o0, off);
        o1 += __shfl_xor(o1, off);
    }
    if (lane == 0) {
        float py = tanhf(o0) * (2.f / 15.f) + ((0.5f + (float)oy) * (1.f / 15.f)) * 2.f - 1.f;
        float px = tanhf(o1) * (2.f / 15.f) + ((0.5f + (float)ox) * (1.f / 15.f)) * 2.f - 1.f;
        posb[bg * 512 + pos * 2 + 0] = py;
        posb[bg * 512 + pos * 2 + 1] = px;
    }
}

// ---------------- K3: bilinear KV sampling ----------------
__global__ void sample_xs_kernel(const float* __restrict__ x, const float* __restrict__ posb,
                                 float* __restrict__ xsb)
{
    const int cc = blockIdx.x, bg = blockIdx.y;
    const int b = bg / GG, g = bg - b * GG;
    const int s = threadIdx.x;
    float py = posb[bg * 512 + s * 2 + 0];
    float px = posb[bg * 512 + s * 2 + 1];
    float xi = (px + 1.f) * 0.5f * 31.f;
    float yi = (py + 1.f) * 0.5f * 31.f;
    float x0f = floorf(xi), y0f = floorf(yi);
    int x0 = (int)x0f, y0 = (int)y0f;
    float wx1 = xi - x0f, wy1 = yi - y0f;
    const float* img = x + ((size_t)(b * CC_ + g * NGC_ + cc)) * HWSZ;
    float acc = 0.f;
#pragma unroll
    for (int t = 0; t < 4; ++t) {
        int iy = y0 + (t >> 1), ix = x0 + (t & 1);
        float w = ((t >> 1) ? wy1 : 1.f - wy1) * ((t & 1) ? wx1 : 1.f - wx1);
        if (iy >= 0 && iy <= 31 && ix >= 0 && ix <= 31)
            acc = fmaf(img[iy * 32 + ix], w, acc);
    }
    xsb[((size_t)(b * CC_ + g * NGC_ + cc)) * NS_ + s] = acc;
}

// ---------------- K5: fused attention, fp16 K via v_dot2, scalar K/V loads ----------------
// grid: (16 qtiles, 48 bh), block 512 = 64 queries(lanes) x 8 sample-groups(waves).
__launch_bounds__(512)
__global__ void attn_kernel(const float* __restrict__ qb, const __half* __restrict__ kt,
                            const float* __restrict__ vt, const float* __restrict__ posb,
                            const float* __restrict__ rpe, float* __restrict__ ao)
{
    // union: phase 1 = rph (fp16 rpe, 8KB) + ps (2KB); phase 2 = lbuf[512] + red[512]f4
    __shared__ float smem[2560];
    __half* rph = (__half*)smem;          // 4096 halfs (3969 used)
    float* ps = smem + 2048;              // 512 floats
    const int bh = blockIdx.y;
    const int b = bh / NHD, h = bh - b * NHD;
    const int bg = b * GG + (h >> 1);
    const int tid = threadIdx.x;

    for (int e = tid; e < RPEW * RPEW; e += 512)
        rph[e] = __float2half(rpe[(size_t)h * (RPEW * RPEW) + e]);
    ps[tid] = posb[bg * 512 + tid];
    __syncthreads();

    const int q = tid & 63;
    const int sgrp = __builtin_amdgcn_readfirstlane(tid >> 6);  // wave-uniform -> scalar K/V loads
    const int qidx = blockIdx.x * 64 + q;
    const int row = qidx >> 5, col = qidx & 31;
    const float gyq = (float)row * (2.f / 31.f) - 1.f;
    const float gxq = (float)col * (2.f / 31.f) - 1.f;

    // Q fragment: fp16 pairs with SCALE pre-folded (for v_dot2)
    half2_t qh[16];
    const float* qg = qb + ((size_t)(b * CC_ + h * HCH)) * HWSZ + qidx;
#pragma unroll
    for (int i = 0; i < 16; ++i) {
        float q0 = qg[(size_t)(2 * i) * HWSZ] * SCALE_;
        float q1 = qg[(size_t)(2 * i + 1) * HWSZ] * SCALE_;
        half2_t hh; hh[0] = (_Float16)q0; hh[1] = (_Float16)q1;
        qh[i] = hh;
    }

    float l = 0.f;
    float oacc[32];
#pragma unroll
    for (int c = 0; c < 32; ++c) oacc[c] = 0.f;

    const unsigned* kb2 = (const unsigned*)kt + ((size_t)bh * NS_) * 16;
    const float* vb2 = vt + ((size_t)bh * NS_) * 32;

    const int s0 = sgrp * 32;
#pragma unroll 2
    for (int s = s0; s < s0 + 32; ++s) {
        const unsigned* kr = kb2 + s * 16;   // wave-uniform -> s_load (64B)
        float d0 = 0.f, d1 = 0.f, d2 = 0.f, d3 = 0.f;
#pragma unroll
        for (int i4 = 0; i4 < 4; ++i4) {
            unsigned ku0 = kr[i4 * 4 + 0], ku1 = kr[i4 * 4 + 1];
            unsigned ku2 = kr[i4 * 4 + 2], ku3 = kr[i4 * 4 + 3];
#ifdef HAS_FDOT2
            d0 = __builtin_amdgcn_fdot2(qh[i4 * 4 + 0], __builtin_bit_cast(half2_t, ku0), d0, false);
            d1 = __builtin_amdgcn_fdot2(qh[i4 * 4 + 1], __builtin_bit_cast(half2_t, ku1), d1, false);
            d2 = __builtin_amdgcn_fdot2(qh[i4 * 4 + 2], __builtin_bit_cast(half2_t, ku2), d2, false);
            d3 = __builtin_amdgcn_fdot2(qh[i4 * 4 + 3], __builtin_bit_cast(half2_t, ku3), d3, false);
#else
            {
                half2_t k0 = __builtin_bit_cast(half2_t, ku0), k1 = __builtin_bit_cast(half2_t, ku1);
                half2_t k2 = __builtin_bit_cast(half2_t, ku2), k3 = __builtin_bit_cast(half2_t, ku3);
                half2_t a0 = qh[i4 * 4 + 0], a1 = qh[i4 * 4 + 1];
                half2_t a2 = qh[i4 * 4 + 2], a3 = qh[i4 * 4 + 3];
                d0 = fmaf((float)a0[0], (float)k0[0], d0); d0 = fmaf((float)a0[1], (float)k0[1], d0);
                d1 = fmaf((float)a1[0], (float)k1[0], d1); d1 = fmaf((float)a1[1], (float)k1[1], d1);
                d2 = fmaf((float)a2[0], (float)k2[0], d2); d2 = fmaf((float)a2[1], (float)k2[1], d2);
                d3 = fmaf((float)a3[0], (float)k3[0], d3); d3 = fmaf((float)a3[1], (float)k3[1], d3);
            }
#endif
        }
        float dot = (d0 + d1) + (d2 + d3);   // already scaled

        float2 pp = *(const float2*)(ps + (s << 1));   // (py, px)
        float dy = (gyq - pp.x) * 0.5f, dx = (gxq - pp.y) * 0.5f;
        float yi = (dy + 1.f) * 31.f,  xi = (dx + 1.f) * 31.f;
        float y0f = floorf(yi), x0f = floorf(xi);
        int iy = (int)y0f, ix = (int)x0f;
        float wy1 = yi - y0f, wx1 = xi - x0f;
        float wy0 = 1.f - wy1, wx0 = 1.f - wx1;
        if ((unsigned)iy > 62u)       wy0 = 0.f;
        if ((unsigned)(iy + 1) > 62u) wy1 = 0.f;
        if ((unsigned)ix > 62u)       wx0 = 0.f;
        if ((unsigned)(ix + 1) > 62u) wx1 = 0.f;
        int ry0 = min(max(iy, 0), 62) * 63;
        int ry1 = min(max(iy + 1, 0), 62) * 63;
        int cx0 = min(max(ix, 0), 62);
        int cx1 = min(max(ix + 1, 0), 62);
        float t00 = __half2float(rph[ry0 + cx0]), t01 = __half2float(rph[ry0 + cx1]);
        float t10 = __half2float(rph[ry1 + cx0]), t11 = __half2float(rph[ry1 + cx1]);
        float bias = wy0 * fmaf(wx0, t00, wx1 * t01)
                   + wy1 * fmaf(wx0, t10, wx1 * t11);

        // logits structurally small: exp without max tracking
        float p = __expf(dot + bias);
        l += p;

        const float* vr = vb2 + s * 32;   // wave-uniform -> s_load
#pragma unroll
        for (int c8 = 0; c8 < 4; ++c8) {
            const int o = c8 * 8;
            float v0 = vr[o + 0], v1 = vr[o + 1], v2 = vr[o + 2], v3 = vr[o + 3];
            float v4 = vr[o + 4], v5 = vr[o + 5], v6 = vr[o + 6], v7 = vr[o + 7];
            oacc[o + 0] = fmaf(p, v0, oacc[o + 0]); oacc[o + 1] = fmaf(p, v1, oacc[o + 1]);
            oacc[o + 2] = fmaf(p, v2, oacc[o + 2]); oacc[o + 3] = fmaf(p, v3, oacc[o + 3]);
            oacc[o + 4] = fmaf(p, v4, oacc[o + 4]); oacc[o + 5] = fmaf(p, v5, oacc[o + 5]);
            oacc[o + 6] = fmaf(p, v6, oacc[o + 6]); oacc[o + 7] = fmaf(p, v7, oacc[o + 7]);
        }
    }

    // ---- merge 8 sample-group waves: plain sums (rph/ps dead now) ----
    __syncthreads();
    float* lbuf = smem;                    // 512 floats
    float4* red = (float4*)(smem + 512);   // 512 float4
    lbuf[tid] = l;
    __syncthreads();
    float L = 0.f;
#pragma unroll
    for (int j = 0; j < 8; ++j) L += lbuf[q + 64 * j];
    float scale = 1.f / L;

    float* og = ao + ((size_t)(b * CC_ + h * HCH)) * HWSZ + qidx;
#pragma unroll
    for (int cb = 0; cb < 8; ++cb) {
        __syncthreads();
        red[tid] = make_float4(oacc[cb * 4 + 0] * scale, oacc[cb * 4 + 1] * scale,
                               oacc[cb * 4 + 2] * scale, oacc[cb * 4 + 3] * scale);
        __syncthreads();
        if (sgrp == 0) {
            float4 sm = red[q];
#pragma unroll
            for (int j = 1; j < 8; ++j) {
                float4 a = red[q + 64 * j];
                sm.x += a.x; sm.y += a.y; sm.z += a.z; sm.w += a.w;
            }
            og[(size_t)(cb * 4 + 0) * HWSZ] = sm.x;
            og[(size_t)(cb * 4 + 1) * HWSZ] = sm.y;
            og[(size_t)(cb * 4 + 2) * HWSZ] = sm.z;
            og[(size_t)(cb * 4 + 3) * HWSZ] = sm.w;
        }
    }
}

extern "C" void kernel_launch(void* const* d_in, const int* in_sizes, int n_in,
                              void* d_out, int out_size, void* d_ws, size_t ws_size,
                              hipStream_t stream) {
    (void)in_sizes; (void)n_in; (void)out_size; (void)ws_size;
    const float* x   = (const float*)d_in[0];
    const float* Wq  = (const float*)d_in[1];
    const float* bq  = (const float*)d_in[2];
    const float* Wk  = (const float*)d_in[3];
    const float* bk  = (const float*)d_in[4];
    const float* Wv  = (const float*)d_in[5];
    const float* bv  = (const float*)d_in[6];
    const float* Wo  = (const float*)d_in[7];
    const float* bo  = (const float*)d_in[8];
    const float* dww = (const float*)d_in[9];
    const float* dwb = (const float*)d_in[10];
    const float* lng = (const float*)d_in[11];
    const float* lnb = (const float*)d_in[12];
    const float* pww = (const float*)d_in[13];
    const float* rpe = (const float*)d_in[14];
    float* out = (float*)d_out;

    float* ws   = (float*)d_ws;
    float* qbuf = ws;                       // 1572864
    float* posb = qbuf + 1572864;           // 12288
    float* xsb  = posb + 12288;             // 393216
    __half* ktb = (__half*)(xsb + 393216);  // 786 KB as fp16 (196608 float slots)
    float* vtb  = xsb + 393216 + 393216;    // 393216 [bh][s][32] fp32
    float* aout = vtb + 393216;             // 1572864
    float* cobuf = aout;                    // 393216, dead before attn writes aout

    conv1x1_cs8<CC_><<<dim3(4, CC_ / 8, BB), 256, 0, stream>>>(Wq, bq, x, qbuf, HWSZ, CC_);
    offset_dw_kernel<<<dim3(NGC_, 24), 256, 0, stream>>>(qbuf, dww, dwb, cobuf);
    offset_fin_kernel<<<dim3(1536), 256, 0, stream>>>(cobuf, lng, lnb, pww, posb);
    sample_xs_kernel<<<dim3(NGC_, 24), 256, 0, stream>>>(x, posb, xsb);
    convkv_kernel<CC_><<<dim3(CC_ / 4, BB), 256, 0, stream>>>(Wk, bk, Wv, bv, xsb, ktb, vtb, NS_);
    attn_kernel<<<dim3(16, BB * NHD), 512, 0, stream>>>(qbuf, ktb, vtb, posb, rpe, aout);
    conv1x1_cs8<CC_><<<dim3(4, CC_ / 8, BB), 256, 0, stream>>>(Wo, bo, aout, out, HWSZ, CC_);
}

// Round 11
// 150.477 us; speedup vs baseline: 2.1329x; 1.1380x over previous
//
#include <hip/hip_runtime.h>
#include <hip/hip_bf16.h>
#include <hip/hip_fp16.h>

#define BB 4
#define CC_ 384
#define HH 32
#define WW 32
#define HWSZ 1024
#define NHD 12
#define HCH 32
#define GG 6
#define NGC_ 64
#define GHD 2
#define HK_ 16
#define WK_ 16
#define NS_ 256
#define RPEW 63
#define SCALE_ 0.17677669529663687f

typedef _Float16 half2_t __attribute__((ext_vector_type(2)));

#if defined(__has_builtin)
#if __has_builtin(__builtin_amdgcn_fdot2)
#define HAS_FDOT2 1
#endif
#endif

// ---------------- K1/K6: LDS-tiled fp32 GEMM conv1x1 ----------------
// Y[b][o][n] = sum_c W[o][c] X[b][c][n] + bias[o]
// BM=64 (o), BN=64 (n), BK=16. block 256 = 16tx x 16ty, each thread 4o x 4n.
// grid: (N/64, OC/64, B)
template<int CIN>
__global__ void conv1x1_gemm(const float* __restrict__ W, const float* __restrict__ bias,
                             const float* __restrict__ X, float* __restrict__ Y,
                             int N, int OC)
{
    __shared__ float Ws[64][20];   // [o][k], padded row 20 for staging-write spread
    __shared__ float Xs[16][64];   // [k][n]
    const int tid = threadIdx.x;
    const int tx = tid & 15, ty = tid >> 4;
    const int otile = blockIdx.y * 64, ntile = blockIdx.x * 64;
    const int b = blockIdx.z;
    const float* Xb = X + (size_t)b * CIN * N + ntile;

    const int wo = tid >> 2, wk = (tid & 3) * 4;       // W stage: o=tid/4, k-quad
    const int xk = tid >> 4, xn = (tid & 15) * 4;      // X stage: k=tid/16, n-quad

    float acc[4][4];
#pragma unroll
    for (int j = 0; j < 4; ++j)
#pragma unroll
        for (int i = 0; i < 4; ++i) acc[j][i] = 0.f;

    for (int k0 = 0; k0 < CIN; k0 += 16) {
        float4 wv = *(const float4*)(W + (size_t)(otile + wo) * CIN + k0 + wk);
        float4 xv = *(const float4*)(Xb + (size_t)(k0 + xk) * N + xn);
        __syncthreads();   // previous-iter reads done before overwrite
        *(float4*)&Ws[wo][wk] = wv;
        *(float4*)&Xs[xk][xn] = xv;
        __syncthreads();
#pragma unroll
        for (int kk = 0; kk < 4; ++kk) {
            float4 x0 = *(const float4*)&Xs[kk * 4 + 0][tx * 4];
            float4 x1 = *(const float4*)&Xs[kk * 4 + 1][tx * 4];
            float4 x2 = *(const float4*)&Xs[kk * 4 + 2][tx * 4];
            float4 x3 = *(const float4*)&Xs[kk * 4 + 3][tx * 4];
#pragma unroll
            for (int j = 0; j < 4; ++j) {
                float4 wf = *(const float4*)&Ws[ty * 4 + j][kk * 4];
                acc[j][0] = fmaf(wf.x, x0.x, acc[j][0]);
                acc[j][1] = fmaf(wf.x, x0.y, acc[j][1]);
                acc[j][2] = fmaf(wf.x, x0.z, acc[j][2]);
                acc[j][3] = fmaf(wf.x, x0.w, acc[j][3]);
                acc[j][0] = fmaf(wf.y, x1.x, acc[j][0]);
                acc[j][1] = fmaf(wf.y, x1.y, acc[j][1]);
                acc[j][2] = fmaf(wf.y, x1.z, acc[j][2]);
                acc[j][3] = fmaf(wf.y, x1.w, acc[j][3]);
                acc[j][0] = fmaf(wf.z, x2.x, acc[j][0]);
                acc[j][1] = fmaf(wf.z, x2.y, acc[j][1]);
                acc[j][2] = fmaf(wf.z, x2.z, acc[j][2]);
                acc[j][3] = fmaf(wf.z, x2.w, acc[j][3]);
                acc[j][0] = fmaf(wf.w, x3.x, acc[j][0]);
                acc[j][1] = fmaf(wf.w, x3.y, acc[j][1]);
                acc[j][2] = fmaf(wf.w, x3.z, acc[j][2]);
                acc[j][3] = fmaf(wf.w, x3.w, acc[j][3]);
            }
        }
    }
#pragma unroll
    for (int j = 0; j < 4; ++j) {
        const int o = otile + ty * 4 + j;
        float bv = bias[o];
        float4 r = make_float4(acc[j][0] + bv, acc[j][1] + bv, acc[j][2] + bv, acc[j][3] + bv);
        *(float4*)(Y + ((size_t)(b * OC + o)) * N + ntile + tx * 4) = r;
    }
}

// ---------------- K4: fused K+V 1x1 conv; K -> fp16 [bh][n][32], V -> fp32 [bh][n][32] ----------------
template<int CIN>
__global__ void convkv_kernel(const float* __restrict__ Wk, const float* __restrict__ bk,
                              const float* __restrict__ Wv, const float* __restrict__ bv,
                              const float* __restrict__ X, __half* __restrict__ Yk,
                              float* __restrict__ Yv, int N)
{
    const int otile = blockIdx.x * 4;          // 4-aligned => same head
    const int b = blockIdx.y;
    const int n = threadIdx.x;
    const float* Xb = X + (size_t)b * CIN * N + n;
    const float* Wkr = Wk + (size_t)otile * CIN;
    const float* Wvr = Wv + (size_t)otile * CIN;

    float ak0 = 0.f, ak1 = 0.f, ak2 = 0.f, ak3 = 0.f;
    float av0 = 0.f, av1 = 0.f, av2 = 0.f, av3 = 0.f;
#pragma unroll 4
    for (int c = 0; c < CIN; ++c) {
        float xv = Xb[(size_t)c * N];
        ak0 = fmaf(Wkr[c], xv, ak0);
        ak1 = fmaf(Wkr[CIN + c], xv, ak1);
        ak2 = fmaf(Wkr[2 * CIN + c], xv, ak2);
        ak3 = fmaf(Wkr[3 * CIN + c], xv, ak3);
        av0 = fmaf(Wvr[c], xv, av0);
        av1 = fmaf(Wvr[CIN + c], xv, av1);
        av2 = fmaf(Wvr[2 * CIN + c], xv, av2);
        av3 = fmaf(Wvr[3 * CIN + c], xv, av3);
    }
    const int h = otile >> 5, cc = otile & 31;
    const size_t obase = (((size_t)(b * NHD + h) * N) + n) * 32 + cc;
    __half2* yk2 = (__half2*)(Yk + obase);
    yk2[0] = __floats2half2_rn(ak0 + bk[otile + 0], ak1 + bk[otile + 1]);
    yk2[1] = __floats2half2_rn(ak2 + bk[otile + 2], ak3 + bk[otile + 3]);
    *(float4*)(Yv + obase) = make_float4(av0 + bv[otile + 0], av1 + bv[otile + 1],
                                         av2 + bv[otile + 2], av3 + bv[otile + 3]);
}

// ---------------- K2a: depthwise conv 5x5 stride 2, transposed output [bg][pos][ch] ----------------
__global__ void offset_dw_kernel(const float* __restrict__ qb, const float* __restrict__ dww,
                                 const float* __restrict__ dwb, float* __restrict__ cobuf)
{
    __shared__ float img[HWSZ];
    const int c = blockIdx.x, bg = blockIdx.y;
    const int b = bg / GG, g = bg - b * GG;
    const int tid = threadIdx.x;
    const float* src = qb + ((size_t)(b * CC_ + g * NGC_ + c)) * HWSZ;
#pragma unroll
    for (int e = tid; e < HWSZ; e += 256) img[e] = src[e];
    __syncthreads();
    const int oy = tid >> 4, ox = tid & 15;
    float s = dwb[c];
    const float* wf = dww + c * 25;
    const int iy0 = oy * 2 - 2, ix0 = ox * 2 - 2;
#pragma unroll
    for (int ky = 0; ky < 5; ++ky) {
        int iy = iy0 + ky;
        if (iy < 0 || iy > 31) continue;
#pragma unroll
        for (int kx = 0; kx < 5; ++kx) {
            int ix = ix0 + kx;
            if (ix < 0 || ix > 31) continue;
            s = fmaf(img[iy * 32 + ix], wf[ky * 5 + kx], s);
        }
    }
    cobuf[((size_t)(bg * 256 + tid)) * NGC_ + c] = s;   // [bg][pos][ch]
}

// ---------------- K2b: LN + GELU + pw + tanh, one wave per position ----------------
__global__ void offset_fin_kernel(const float* __restrict__ cobuf, const float* __restrict__ lng,
                                  const float* __restrict__ lnb, const float* __restrict__ pww,
                                  float* __restrict__ posb)
{
    const int lane = threadIdx.x & 63;
    const int gpos = blockIdx.x * 4 + (threadIdx.x >> 6);   // 0..6143
    const int bg = gpos >> 8, pos = gpos & 255;
    const int oy = (pos >> 4), ox = pos & 15;

    float v = cobuf[(size_t)gpos * NGC_ + lane];
    float s1 = v, s2 = v * v;
#pragma unroll
    for (int off = 32; off >= 1; off >>= 1) {
        s1 += __shfl_xor(s1, off);
        s2 += __shfl_xor(s2, off);
    }
    float mu = s1 * (1.f / 64.f);
    float var = s2 * (1.f / 64.f) - mu * mu;
    float rstd = rsqrtf(var + 1e-5f);
    float t = (v - mu) * rstd * lng[lane] + lnb[lane];
    float gv = 0.5f * t * (1.f + erff(t * 0.70710678118654752f));
    float o0 = pww[lane] * gv;
    float o1 = pww[64 + lane] * gv;
#pragma unroll
    for (int off = 32; off >= 1; off >>= 1) {
        o0 += __shfl_xor(o0, off);
        o1 += __shfl_xor(o1, off);
    }
    if (lane == 0) {
        float py = tanhf(o0) * (2.f / 15.f) + ((0.5f + (float)oy) * (1.f / 15.f)) * 2.f - 1.f;
        float px = tanhf(o1) * (2.f / 15.f) + ((0.5f + (float)ox) * (1.f / 15.f)) * 2.f - 1.f;
        posb[bg * 512 + pos * 2 + 0] = py;
        posb[bg * 512 + pos * 2 + 1] = px;
    }
}

// ---------------- K3: bilinear KV sampling ----------------
__global__ void sample_xs_kernel(const float* __restrict__ x, const float* __restrict__ posb,
                                 float* __restrict__ xsb)
{
    const int cc = blockIdx.x, bg = blockIdx.y;
    const int b = bg / GG, g = bg - b * GG;
    const int s = threadIdx.x;
    float py = posb[bg * 512 + s * 2 + 0];
    float px = posb[bg * 512 + s * 2 + 1];
    float xi = (px + 1.f) * 0.5f * 31.f;
    float yi = (py + 1.f) * 0.5f * 31.f;
    float x0f = floorf(xi), y0f = floorf(yi);
    int x0 = (int)x0f, y0 = (int)y0f;
    float wx1 = xi - x0f, wy1 = yi - y0f;
    const float* img = x + ((size_t)(b * CC_ + g * NGC_ + cc)) * HWSZ;
    float acc = 0.f;
#pragma unroll
    for (int t = 0; t < 4; ++t) {
        int iy = y0 + (t >> 1), ix = x0 + (t & 1);
        float w = ((t >> 1) ? wy1 : 1.f - wy1) * ((t & 1) ? wx1 : 1.f - wx1);
        if (iy >= 0 && iy <= 31 && ix >= 0 && ix <= 31)
            acc = fmaf(img[iy * 32 + ix], w, acc);
    }
    xsb[((size_t)(b * CC_ + g * NGC_ + cc)) * NS_ + s] = acc;
}

// ---------------- K5: fused attention, fp16 K via v_dot2, scalar K/V loads ----------------
// grid: (16 qtiles, 48 bh), block 512 = 64 queries(lanes) x 8 sample-groups(waves).
__launch_bounds__(512)
__global__ void attn_kernel(const float* __restrict__ qb, const __half* __restrict__ kt,
                            const float* __restrict__ vt, const float* __restrict__ posb,
                            const float* __restrict__ rpe, float* __restrict__ ao)
{
    // union: phase 1 = rph (fp16 rpe, 8KB) + ps (2KB); phase 2 = lbuf[512] + red[512]f4
    __shared__ float smem[2560];
    __half* rph = (__half*)smem;          // 4096 halfs (3969 used)
    float* ps = smem + 2048;              // 512 floats
    const int bh = blockIdx.y;
    const int b = bh / NHD, h = bh - b * NHD;
    const int bg = b * GG + (h >> 1);
    const int tid = threadIdx.x;

    for (int e = tid; e < RPEW * RPEW; e += 512)
        rph[e] = __float2half(rpe[(size_t)h * (RPEW * RPEW) + e]);
    ps[tid] = posb[bg * 512 + tid];
    __syncthreads();

    const int q = tid & 63;
    const int sgrp = __builtin_amdgcn_readfirstlane(tid >> 6);  // wave-uniform -> scalar K/V loads
    const int qidx = blockIdx.x * 64 + q;
    const int row = qidx >> 5, col = qidx & 31;
    const float gyq = (float)row * (2.f / 31.f) - 1.f;
    const float gxq = (float)col * (2.f / 31.f) - 1.f;

    // Q fragment: fp16 pairs with SCALE pre-folded (for v_dot2)
    half2_t qh[16];
    const float* qg = qb + ((size_t)(b * CC_ + h * HCH)) * HWSZ + qidx;
#pragma unroll
    for (int i = 0; i < 16; ++i) {
        float q0 = qg[(size_t)(2 * i) * HWSZ] * SCALE_;
        float q1 = qg[(size_t)(2 * i + 1) * HWSZ] * SCALE_;
        half2_t hh; hh[0] = (_Float16)q0; hh[1] = (_Float16)q1;
        qh[i] = hh;
    }

    float l = 0.f;
    float oacc[32];
#pragma unroll
    for (int c = 0; c < 32; ++c) oacc[c] = 0.f;

    const unsigned* kb2 = (const unsigned*)kt + ((size_t)bh * NS_) * 16;
    const float* vb2 = vt + ((size_t)bh * NS_) * 32;

    const int s0 = sgrp * 32;
#pragma unroll 2
    for (int s = s0; s < s0 + 32; ++s) {
        const unsigned* kr = kb2 + s * 16;   // wave-uniform -> s_load (64B)
        float d0 = 0.f, d1 = 0.f, d2 = 0.f, d3 = 0.f;
#pragma unroll
        for (int i4 = 0; i4 < 4; ++i4) {
            unsigned ku0 = kr[i4 * 4 + 0], ku1 = kr[i4 * 4 + 1];
            unsigned ku2 = kr[i4 * 4 + 2], ku3 = kr[i4 * 4 + 3];
#ifdef HAS_FDOT2
            d0 = __builtin_amdgcn_fdot2(qh[i4 * 4 + 0], __builtin_bit_cast(half2_t, ku0), d0, false);
            d1 = __builtin_amdgcn_fdot2(qh[i4 * 4 + 1], __builtin_bit_cast(half2_t, ku1), d1, false);
            d2 = __builtin_amdgcn_fdot2(qh[i4 * 4 + 2], __builtin_bit_cast(half2_t, ku2), d2, false);
            d3 = __builtin_amdgcn_fdot2(qh[i4 * 4 + 3], __builtin_bit_cast(half2_t, ku3), d3, false);
#else
            {
                half2_t k0 = __builtin_bit_cast(half2_t, ku0), k1 = __builtin_bit_cast(half2_t, ku1);
                half2_t k2 = __builtin_bit_cast(half2_t, ku2), k3 = __builtin_bit_cast(half2_t, ku3);
                half2_t a0 = qh[i4 * 4 + 0], a1 = qh[i4 * 4 + 1];
                half2_t a2 = qh[i4 * 4 + 2], a3 = qh[i4 * 4 + 3];
                d0 = fmaf((float)a0[0], (float)k0[0], d0); d0 = fmaf((float)a0[1], (float)k0[1], d0);
                d1 = fmaf((float)a1[0], (float)k1[0], d1); d1 = fmaf((float)a1[1], (float)k1[1], d1);
                d2 = fmaf((float)a2[0], (float)k2[0], d2); d2 = fmaf((float)a2[1], (float)k2[1], d2);
                d3 = fmaf((float)a3[0], (float)k3[0], d3); d3 = fmaf((float)a3[1], (float)k3[1], d3);
            }
#endif
        }
        float dot = (d0 + d1) + (d2 + d3);   // already scaled

        float2 pp = *(const float2*)(ps + (s << 1));   // (py, px)
        float dy = (gyq - pp.x) * 0.5f, dx = (gxq - pp.y) * 0.5f;
        float yi = (dy + 1.f) * 31.f,  xi = (dx + 1.f) * 31.f;
        float y0f = floorf(yi), x0f = floorf(xi);
        int iy = (int)y0f, ix = (int)x0f;
        float wy1 = yi - y0f, wx1 = xi - x0f;
        float wy0 = 1.f - wy1, wx0 = 1.f - wx1;
        if ((unsigned)iy > 62u)       wy0 = 0.f;
        if ((unsigned)(iy + 1) > 62u) wy1 = 0.f;
        if ((unsigned)ix > 62u)       wx0 = 0.f;
        if ((unsigned)(ix + 1) > 62u) wx1 = 0.f;
        int ry0 = min(max(iy, 0), 62) * 63;
        int ry1 = min(max(iy + 1, 0), 62) * 63;
        int cx0 = min(max(ix, 0), 62);
        int cx1 = min(max(ix + 1, 0), 62);
        float t00 = __half2float(rph[ry0 + cx0]), t01 = __half2float(rph[ry0 + cx1]);
        float t10 = __half2float(rph[ry1 + cx0]), t11 = __half2float(rph[ry1 + cx1]);
        float bias = wy0 * fmaf(wx0, t00, wx1 * t01)
                   + wy1 * fmaf(wx0, t10, wx1 * t11);

        // logits structurally small: exp without max tracking
        float p = __expf(dot + bias);
        l += p;

        const float* vr = vb2 + s * 32;   // wave-uniform -> s_load
#pragma unroll
        for (int c8 = 0; c8 < 4; ++c8) {
            const int o = c8 * 8;
            float v0 = vr[o + 0], v1 = vr[o + 1], v2 = vr[o + 2], v3 = vr[o + 3];
            float v4 = vr[o + 4], v5 = vr[o + 5], v6 = vr[o + 6], v7 = vr[o + 7];
            oacc[o + 0] = fmaf(p, v0, oacc[o + 0]); oacc[o + 1] = fmaf(p, v1, oacc[o + 1]);
            oacc[o + 2] = fmaf(p, v2, oacc[o + 2]); oacc[o + 3] = fmaf(p, v3, oacc[o + 3]);
            oacc[o + 4] = fmaf(p, v4, oacc[o + 4]); oacc[o + 5] = fmaf(p, v5, oacc[o + 5]);
            oacc[o + 6] = fmaf(p, v6, oacc[o + 6]); oacc[o + 7] = fmaf(p, v7, oacc[o + 7]);
        }
    }

    // ---- merge 8 sample-group waves: plain sums (rph/ps dead now) ----
    __syncthreads();
    float* lbuf = smem;                    // 512 floats
    float4* red = (float4*)(smem + 512);   // 512 float4
    lbuf[tid] = l;
    __syncthreads();
    float L = 0.f;
#pragma unroll
    for (int j = 0; j < 8; ++j) L += lbuf[q + 64 * j];
    float scale = 1.f / L;

    float* og = ao + ((size_t)(b * CC_ + h * HCH)) * HWSZ + qidx;
#pragma unroll
    for (int cb = 0; cb < 8; ++cb) {
        __syncthreads();
        red[tid] = make_float4(oacc[cb * 4 + 0] * scale, oacc[cb * 4 + 1] * scale,
                               oacc[cb * 4 + 2] * scale, oacc[cb * 4 + 3] * scale);
        __syncthreads();
        if (sgrp == 0) {
            float4 sm = red[q];
#pragma unroll
            for (int j = 1; j < 8; ++j) {
                float4 a = red[q + 64 * j];
                sm.x += a.x; sm.y += a.y; sm.z += a.z; sm.w += a.w;
            }
            og[(size_t)(cb * 4 + 0) * HWSZ] = sm.x;
            og[(size_t)(cb * 4 + 1) * HWSZ] = sm.y;
            og[(size_t)(cb * 4 + 2) * HWSZ] = sm.z;
            og[(size_t)(cb * 4 + 3) * HWSZ] = sm.w;
        }
    }
}

extern "C" void kernel_launch(void* const* d_in, const int* in_sizes, int n_in,
                              void* d_out, int out_size, void* d_ws, size_t ws_size,
                              hipStream_t stream) {
    (void)in_sizes; (void)n_in; (void)out_size; (void)ws_size;
    const float* x   = (const float*)d_in[0];
    const float* Wq  = (const float*)d_in[1];
    const float* bq  = (const float*)d_in[2];
    const float* Wk  = (const float*)d_in[3];
    const float* bk  = (const float*)d_in[4];
    const float* Wv  = (const float*)d_in[5];
    const float* bv  = (const float*)d_in[6];
    const float* Wo  = (const float*)d_in[7];
    const float* bo  = (const float*)d_in[8];
    const float* dww = (const float*)d_in[9];
    const float* dwb = (const float*)d_in[10];
    const float* lng = (const float*)d_in[11];
    const float* lnb = (const float*)d_in[12];
    const float* pww = (const float*)d_in[13];
    const float* rpe = (const float*)d_in[14];
    float* out = (float*)d_out;

    float* ws   = (float*)d_ws;
    float* qbuf = ws;                       // 1572864
    float* posb = qbuf + 1572864;           // 12288
    float* xsb  = posb + 12288;             // 393216
    __half* ktb = (__half*)(xsb + 393216);  // 786 KB as fp16 (196608 float slots)
    float* vtb  = xsb + 393216 + 393216;    // 393216 [bh][s][32] fp32
    float* aout = vtb + 393216;             // 1572864
    float* cobuf = aout;                    // 393216, dead before attn writes aout

    conv1x1_gemm<CC_><<<dim3(HWSZ / 64, CC_ / 64, BB), 256, 0, stream>>>(Wq, bq, x, qbuf, HWSZ, CC_);
    offset_dw_kernel<<<dim3(NGC_, 24), 256, 0, stream>>>(qbuf, dww, dwb, cobuf);
    offset_fin_kernel<<<dim3(1536), 256, 0, stream>>>(cobuf, lng, lnb, pww, posb);
    sample_xs_kernel<<<dim3(NGC_, 24), 256, 0, stream>>>(x, posb, xsb);
    convkv_kernel<CC_><<<dim3(CC_ / 4, BB), 256, 0, stream>>>(Wk, bk, Wv, bv, xsb, ktb, vtb, NS_);
    attn_kernel<<<dim3(16, BB * NHD), 512, 0, stream>>>(qbuf, ktb, vtb, posb, rpe, aout);
    conv1x1_gemm<CC_><<<dim3(HWSZ / 64, CC_ / 64, BB), 256, 0, stream>>>(Wo, bo, aout, out, HWSZ, CC_);
}

// Round 12
// 134.483 us; speedup vs baseline: 2.3865x; 1.1189x over previous
//
#include <hip/hip_runtime.h>
#include <hip/hip_bf16.h>
#include <hip/hip_fp16.h>

#define BB 4
#define CC_ 384
#define HH 32
#define WW 32
#define HWSZ 1024
#define NHD 12
#define HCH 32
#define GG 6
#define NGC_ 64
#define GHD 2
#define HK_ 16
#define WK_ 16
#define NS_ 256
#define RPEW 63
#define SCALE_ 0.17677669529663687f

typedef _Float16 half2_t __attribute__((ext_vector_type(2)));
typedef _Float16 half8_t __attribute__((ext_vector_type(8)));
typedef float f32x4_t __attribute__((ext_vector_type(4)));

#if defined(__has_builtin)
#if __has_builtin(__builtin_amdgcn_fdot2)
#define HAS_FDOT2 1
#endif
#endif

// ---------------- K1/K6: MFMA fp16 conv1x1 (no LDS, no barriers) ----------------
// Y[b][o][n] = sum_c W[o][c] X[b][c][n] + bias[o]
// Wave tile: 16 (o) x 64 (n), 4 mfma_f32_16x16x32_f16 frags; block = 4 waves on o.
// grid: (N/64, OC/64, B). Fragment maps (m89/m91-verified family):
//   A: row=l&15, k=(l>>4)*8+j ; B: col=l&15, same k ; D: row=(l>>4)*4+r, col=l&15
template<int CIN>
__global__ __launch_bounds__(256)
void conv1x1_mfma(const float* __restrict__ W, const float* __restrict__ bias,
                  const float* __restrict__ X, float* __restrict__ Y, int N, int OC)
{
    const int tid = threadIdx.x;
    const int wv = tid >> 6;
    const int lane = tid & 63;
    const int l15 = lane & 15, lhi = lane >> 4;
    const int otile = blockIdx.y * 64 + wv * 16;
    const int ntile = blockIdx.x * 64;
    const int b = blockIdx.z;

    const float* Wp = W + (size_t)(otile + l15) * CIN + lhi * 8;
    const float* Xp = X + (size_t)b * CIN * N + (size_t)(lhi * 8) * N + ntile + l15;

    f32x4_t acc0 = {0.f, 0.f, 0.f, 0.f}, acc1 = {0.f, 0.f, 0.f, 0.f};
    f32x4_t acc2 = {0.f, 0.f, 0.f, 0.f}, acc3 = {0.f, 0.f, 0.f, 0.f};

    for (int k0 = 0; k0 < CIN; k0 += 32) {
        // A fragment: W[otile + l15][k0 + lhi*8 + j]
        float4 wa = *(const float4*)(Wp + k0);
        float4 wb = *(const float4*)(Wp + k0 + 4);
        half8_t af;
        af[0] = (_Float16)wa.x; af[1] = (_Float16)wa.y;
        af[2] = (_Float16)wa.z; af[3] = (_Float16)wa.w;
        af[4] = (_Float16)wb.x; af[5] = (_Float16)wb.y;
        af[6] = (_Float16)wb.z; af[7] = (_Float16)wb.w;
        // B fragments: X[k0 + lhi*8 + j][ntile + t*16 + l15]
        const float* Xk = Xp + (size_t)k0 * N;
        half8_t bf0, bf1, bf2, bf3;
#pragma unroll
        for (int j = 0; j < 8; ++j) {
            const float* xr = Xk + (size_t)j * N;
            bf0[j] = (_Float16)xr[0];
            bf1[j] = (_Float16)xr[16];
            bf2[j] = (_Float16)xr[32];
            bf3[j] = (_Float16)xr[48];
        }
        acc0 = __builtin_amdgcn_mfma_f32_16x16x32_f16(af, bf0, acc0, 0, 0, 0);
        acc1 = __builtin_amdgcn_mfma_f32_16x16x32_f16(af, bf1, acc1, 0, 0, 0);
        acc2 = __builtin_amdgcn_mfma_f32_16x16x32_f16(af, bf2, acc2, 0, 0, 0);
        acc3 = __builtin_amdgcn_mfma_f32_16x16x32_f16(af, bf3, acc3, 0, 0, 0);
    }
    float bv[4];
#pragma unroll
    for (int r = 0; r < 4; ++r) bv[r] = bias[otile + lhi * 4 + r];
#pragma unroll
    for (int r = 0; r < 4; ++r) {
        float* yr = Y + ((size_t)(b * OC + otile + lhi * 4 + r)) * N + ntile + l15;
        yr[0]  = acc0[r] + bv[r];
        yr[16] = acc1[r] + bv[r];
        yr[32] = acc2[r] + bv[r];
        yr[48] = acc3[r] + bv[r];
    }
}

// ---------------- K4: fused K+V 1x1 conv; K -> fp16 [bh][n][32], V -> fp32 [bh][n][32] ----------------
template<int CIN>
__global__ void convkv_kernel(const float* __restrict__ Wk, const float* __restrict__ bk,
                              const float* __restrict__ Wv, const float* __restrict__ bv,
                              const float* __restrict__ X, __half* __restrict__ Yk,
                              float* __restrict__ Yv, int N)
{
    const int otile = blockIdx.x * 4;          // 4-aligned => same head
    const int b = blockIdx.y;
    const int n = threadIdx.x;
    const float* Xb = X + (size_t)b * CIN * N + n;
    const float* Wkr = Wk + (size_t)otile * CIN;
    const float* Wvr = Wv + (size_t)otile * CIN;

    float ak0 = 0.f, ak1 = 0.f, ak2 = 0.f, ak3 = 0.f;
    float av0 = 0.f, av1 = 0.f, av2 = 0.f, av3 = 0.f;
#pragma unroll 4
    for (int c = 0; c < CIN; ++c) {
        float xv = Xb[(size_t)c * N];
        ak0 = fmaf(Wkr[c], xv, ak0);
        ak1 = fmaf(Wkr[CIN + c], xv, ak1);
        ak2 = fmaf(Wkr[2 * CIN + c], xv, ak2);
        ak3 = fmaf(Wkr[3 * CIN + c], xv, ak3);
        av0 = fmaf(Wvr[c], xv, av0);
        av1 = fmaf(Wvr[CIN + c], xv, av1);
        av2 = fmaf(Wvr[2 * CIN + c], xv, av2);
        av3 = fmaf(Wvr[3 * CIN + c], xv, av3);
    }
    const int h = otile >> 5, cc = otile & 31;
    const size_t obase = (((size_t)(b * NHD + h) * N) + n) * 32 + cc;
    __half2* yk2 = (__half2*)(Yk + obase);
    yk2[0] = __floats2half2_rn(ak0 + bk[otile + 0], ak1 + bk[otile + 1]);
    yk2[1] = __floats2half2_rn(ak2 + bk[otile + 2], ak3 + bk[otile + 3]);
    *(float4*)(Yv + obase) = make_float4(av0 + bv[otile + 0], av1 + bv[otile + 1],
                                         av2 + bv[otile + 2], av3 + bv[otile + 3]);
}

// ---------------- K2a: depthwise conv 5x5 stride 2, transposed output [bg][pos][ch] ----------------
__global__ void offset_dw_kernel(const float* __restrict__ qb, const float* __restrict__ dww,
                                 const float* __restrict__ dwb, float* __restrict__ cobuf)
{
    __shared__ float img[HWSZ];
    const int c = blockIdx.x, bg = blockIdx.y;
    const int b = bg / GG, g = bg - b * GG;
    const int tid = threadIdx.x;
    const float* src = qb + ((size_t)(b * CC_ + g * NGC_ + c)) * HWSZ;
#pragma unroll
    for (int e = tid; e < HWSZ; e += 256) img[e] = src[e];
    __syncthreads();
    const int oy = tid >> 4, ox = tid & 15;
    float s = dwb[c];
    const float* wf = dww + c * 25;
    const int iy0 = oy * 2 - 2, ix0 = ox * 2 - 2;
#pragma unroll
    for (int ky = 0; ky < 5; ++ky) {
        int iy = iy0 + ky;
        if (iy < 0 || iy > 31) continue;
#pragma unroll
        for (int kx = 0; kx < 5; ++kx) {
            int ix = ix0 + kx;
            if (ix < 0 || ix > 31) continue;
            s = fmaf(img[iy * 32 + ix], wf[ky * 5 + kx], s);
        }
    }
    cobuf[((size_t)(bg * 256 + tid)) * NGC_ + c] = s;   // [bg][pos][ch]
}

// ---------------- K2b: LN + GELU + pw + tanh, one wave per position ----------------
__global__ void offset_fin_kernel(const float* __restrict__ cobuf, const float* __restrict__ lng,
                                  const float* __restrict__ lnb, const float* __restrict__ pww,
                                  float* __restrict__ posb)
{
    const int lane = threadIdx.x & 63;
    const int gpos = blockIdx.x * 4 + (threadIdx.x >> 6);   // 0..6143
    const int bg = gpos >> 8, pos = gpos & 255;
    const int oy = (pos >> 4), ox = pos & 15;

    float v = cobuf[(size_t)gpos * NGC_ + lane];
    float s1 = v, s2 = v * v;
#pragma unroll
    for (int off = 32; off >= 1; off >>= 1) {
        s1 += __shfl_xor(s1, off);
        s2 += __shfl_xor(s2, off);
    }
    float mu = s1 * (1.f / 64.f);
    float var = s2 * (1.f / 64.f) - mu * mu;
    float rstd = rsqrtf(var + 1e-5f);
    float t = (v - mu) * rstd * lng[lane] + lnb[lane];
    float gv = 0.5f * t * (1.f + erff(t * 0.70710678118654752f));
    float o0 = pww[lane] * gv;
    float o1 = pww[64 + lane] * gv;
#pragma unroll
    for (int off = 32; off >= 1; off >>= 1) {
        o0 += __shfl_xor(o0, off);
        o1 += __shfl_xor(o1, off);
    }
    if (lane == 0) {
        float py = tanhf(o0) * (2.f / 15.f) + ((0.5f + (float)oy) * (1.f / 15.f)) * 2.f - 1.f;
        float px = tanhf(o1) * (2.f / 15.f) + ((0.5f + (float)ox) * (1.f / 15.f)) * 2.f - 1.f;
        posb[bg * 512 + pos * 2 + 0] = py;
        posb[bg * 512 + pos * 2 + 1] = px;
    }
}

// ---------------- K3: bilinear KV sampling ----------------
__global__ void sample_xs_kernel(const float* __restrict__ x, const float* __restrict__ posb,
                                 float* __restrict__ xsb)
{
    const int cc = blockIdx.x, bg = blockIdx.y;
    const int b = bg / GG, g = bg - b * GG;
    const int s = threadIdx.x;
    float py = posb[bg * 512 + s * 2 + 0];
    float px = posb[bg * 512 + s * 2 + 1];
    float xi = (px + 1.f) * 0.5f * 31.f;
    float yi = (py + 1.f) * 0.5f * 31.f;
    float x0f = floorf(xi), y0f = floorf(yi);
    int x0 = (int)x0f, y0 = (int)y0f;
    float wx1 = xi - x0f, wy1 = yi - y0f;
    const float* img = x + ((size_t)(b * CC_ + g * NGC_ + cc)) * HWSZ;
    float acc = 0.f;
#pragma unroll
    for (int t = 0; t < 4; ++t) {
        int iy = y0 + (t >> 1), ix = x0 + (t & 1);
        float w = ((t >> 1) ? wy1 : 1.f - wy1) * ((t & 1) ? wx1 : 1.f - wx1);
        if (iy >= 0 && iy <= 31 && ix >= 0 && ix <= 31)
            acc = fmaf(img[iy * 32 + ix], w, acc);
    }
    xsb[((size_t)(b * CC_ + g * NGC_ + cc)) * NS_ + s] = acc;
}

// ---------------- K5: fused attention, fp16 K via v_dot2, scalar K/V loads ----------------
// grid: (16 qtiles, 48 bh), block 512 = 64 queries(lanes) x 8 sample-groups(waves).
__launch_bounds__(512)
__global__ void attn_kernel(const float* __restrict__ qb, const __half* __restrict__ kt,
                            const float* __restrict__ vt, const float* __restrict__ posb,
                            const float* __restrict__ rpe, float* __restrict__ ao)
{
    // union: phase 1 = rph (fp16 rpe, 8KB) + ps (2KB); phase 2 = lbuf[512] + red[512]f4
    __shared__ float smem[2560];
    __half* rph = (__half*)smem;          // 4096 halfs (3969 used)
    float* ps = smem + 2048;              // 512 floats
    const int bh = blockIdx.y;
    const int b = bh / NHD, h = bh - b * NHD;
    const int bg = b * GG + (h >> 1);
    const int tid = threadIdx.x;

    for (int e = tid; e < RPEW * RPEW; e += 512)
        rph[e] = __float2half(rpe[(size_t)h * (RPEW * RPEW) + e]);
    ps[tid] = posb[bg * 512 + tid];
    __syncthreads();

    const int q = tid & 63;
    const int sgrp = __builtin_amdgcn_readfirstlane(tid >> 6);  // wave-uniform -> scalar K/V loads
    const int qidx = blockIdx.x * 64 + q;
    const int row = qidx >> 5, col = qidx & 31;
    const float gyq = (float)row * (2.f / 31.f) - 1.f;
    const float gxq = (float)col * (2.f / 31.f) - 1.f;

    // Q fragment: fp16 pairs with SCALE pre-folded (for v_dot2)
    half2_t qh[16];
    const float* qg = qb + ((size_t)(b * CC_ + h * HCH)) * HWSZ + qidx;
#pragma unroll
    for (int i = 0; i < 16; ++i) {
        float q0 = qg[(size_t)(2 * i) * HWSZ] * SCALE_;
        float q1 = qg[(size_t)(2 * i + 1) * HWSZ] * SCALE_;
        half2_t hh; hh[0] = (_Float16)q0; hh[1] = (_Float16)q1;
        qh[i] = hh;
    }

    float l = 0.f;
    float oacc[32];
#pragma unroll
    for (int c = 0; c < 32; ++c) oacc[c] = 0.f;

    const unsigned* kb2 = (const unsigned*)kt + ((size_t)bh * NS_) * 16;
    const float* vb2 = vt + ((size_t)bh * NS_) * 32;

    const int s0 = sgrp * 32;
#pragma unroll 2
    for (int s = s0; s < s0 + 32; ++s) {
        const unsigned* kr = kb2 + s * 16;   // wave-uniform -> s_load (64B)
        float d0 = 0.f, d1 = 0.f, d2 = 0.f, d3 = 0.f;
#pragma unroll
        for (int i4 = 0; i4 < 4; ++i4) {
            unsigned ku0 = kr[i4 * 4 + 0], ku1 = kr[i4 * 4 + 1];
            unsigned ku2 = kr[i4 * 4 + 2], ku3 = kr[i4 * 4 + 3];
#ifdef HAS_FDOT2
            d0 = __builtin_amdgcn_fdot2(qh[i4 * 4 + 0], __builtin_bit_cast(half2_t, ku0), d0, false);
            d1 = __builtin_amdgcn_fdot2(qh[i4 * 4 + 1], __builtin_bit_cast(half2_t, ku1), d1, false);
            d2 = __builtin_amdgcn_fdot2(qh[i4 * 4 + 2], __builtin_bit_cast(half2_t, ku2), d2, false);
            d3 = __builtin_amdgcn_fdot2(qh[i4 * 4 + 3], __builtin_bit_cast(half2_t, ku3), d3, false);
#else
            {
                half2_t k0 = __builtin_bit_cast(half2_t, ku0), k1 = __builtin_bit_cast(half2_t, ku1);
                half2_t k2 = __builtin_bit_cast(half2_t, ku2), k3 = __builtin_bit_cast(half2_t, ku3);
                half2_t a0 = qh[i4 * 4 + 0], a1 = qh[i4 * 4 + 1];
                half2_t a2 = qh[i4 * 4 + 2], a3 = qh[i4 * 4 + 3];
                d0 = fmaf((float)a0[0], (float)k0[0], d0); d0 = fmaf((float)a0[1], (float)k0[1], d0);
                d1 = fmaf((float)a1[0], (float)k1[0], d1); d1 = fmaf((float)a1[1], (float)k1[1], d1);
                d2 = fmaf((float)a2[0], (float)k2[0], d2); d2 = fmaf((float)a2[1], (float)k2[1], d2);
                d3 = fmaf((float)a3[0], (float)k3[0], d3); d3 = fmaf((float)a3[1], (float)k3[1], d3);
            }
#endif
        }
        float dot = (d0 + d1) + (d2 + d3);   // already scaled

        float2 pp = *(const float2*)(ps + (s << 1));   // (py, px)
        float dy = (gyq - pp.x) * 0.5f, dx = (gxq - pp.y) * 0.5f;
        float yi = (dy + 1.f) * 31.f,  xi = (dx + 1.f) * 31.f;
        float y0f = floorf(yi), x0f = floorf(xi);
        int iy = (int)y0f, ix = (int)x0f;
        float wy1 = yi - y0f, wx1 = xi - x0f;
        float wy0 = 1.f - wy1, wx0 = 1.f - wx1;
        if ((unsigned)iy > 62u)       wy0 = 0.f;
        if ((unsigned)(iy + 1) > 62u) wy1 = 0.f;
        if ((unsigned)ix > 62u)       wx0 = 0.f;
        if ((unsigned)(ix + 1) > 62u) wx1 = 0.f;
        int ry0 = min(max(iy, 0), 62) * 63;
        int ry1 = min(max(iy + 1, 0), 62) * 63;
        int cx0 = min(max(ix, 0), 62);
        int cx1 = min(max(ix + 1, 0), 62);
        float t00 = __half2float(rph[ry0 + cx0]), t01 = __half2float(rph[ry0 + cx1]);
        float t10 = __half2float(rph[ry1 + cx0]), t11 = __half2float(rph[ry1 + cx1]);
        float bias = wy0 * fmaf(wx0, t00, wx1 * t01)
                   + wy1 * fmaf(wx0, t10, wx1 * t11);

        // logits structurally small: exp without max tracking
        float p = __expf(dot + bias);
        l += p;

        const float* vr = vb2 + s * 32;   // wave-uniform -> s_load
#pragma unroll
        for (int c8 = 0; c8 < 4; ++c8) {
            const int o = c8 * 8;
            float v0 = vr[o + 0], v1 = vr[o + 1], v2 = vr[o + 2], v3 = vr[o + 3];
            float v4 = vr[o + 4], v5 = vr[o + 5], v6 = vr[o + 6], v7 = vr[o + 7];
            oacc[o + 0] = fmaf(p, v0, oacc[o + 0]); oacc[o + 1] = fmaf(p, v1, oacc[o + 1]);
            oacc[o + 2] = fmaf(p, v2, oacc[o + 2]); oacc[o + 3] = fmaf(p, v3, oacc[o + 3]);
            oacc[o + 4] = fmaf(p, v4, oacc[o + 4]); oacc[o + 5] = fmaf(p, v5, oacc[o + 5]);
            oacc[o + 6] = fmaf(p, v6, oacc[o + 6]); oacc[o + 7] = fmaf(p, v7, oacc[o + 7]);
        }
    }

    // ---- merge 8 sample-group waves: plain sums (rph/ps dead now) ----
    __syncthreads();
    float* lbuf = smem;                    // 512 floats
    float4* red = (float4*)(smem + 512);   // 512 float4
    lbuf[tid] = l;
    __syncthreads();
    float L = 0.f;
#pragma unroll
    for (int j = 0; j < 8; ++j) L += lbuf[q + 64 * j];
    float scale = 1.f / L;

    float* og = ao + ((size_t)(b * CC_ + h * HCH)) * HWSZ + qidx;
#pragma unroll
    for (int cb = 0; cb < 8; ++cb) {
        __syncthreads();
        red[tid] = make_float4(oacc[cb * 4 + 0] * scale, oacc[cb * 4 + 1] * scale,
                               oacc[cb * 4 + 2] * scale, oacc[cb * 4 + 3] * scale);
        __syncthreads();
        if (sgrp == 0) {
            float4 sm = red[q];
#pragma unroll
            for (int j = 1; j < 8; ++j) {
                float4 a = red[q + 64 * j];
                sm.x += a.x; sm.y += a.y; sm.z += a.z; sm.w += a.w;
            }
            og[(size_t)(cb * 4 + 0) * HWSZ] = sm.x;
            og[(size_t)(cb * 4 + 1) * HWSZ] = sm.y;
            og[(size_t)(cb * 4 + 2) * HWSZ] = sm.z;
            og[(size_t)(cb * 4 + 3) * HWSZ] = sm.w;
        }
    }
}

extern "C" void kernel_launch(void* const* d_in, const int* in_sizes, int n_in,
                              void* d_out, int out_size, void* d_ws, size_t ws_size,
                              hipStream_t stream) {
    (void)in_sizes; (void)n_in; (void)out_size; (void)ws_size;
    const float* x   = (const float*)d_in[0];
    const float* Wq  = (const float*)d_in[1];
    const float* bq  = (const float*)d_in[2];
    const float* Wk  = (const float*)d_in[3];
    const float* bk  = (const float*)d_in[4];
    const float* Wv  = (const float*)d_in[5];
    const float* bv  = (const float*)d_in[6];
    const float* Wo  = (const float*)d_in[7];
    const float* bo  = (const float*)d_in[8];
    const float* dww = (const float*)d_in[9];
    const float* dwb = (const float*)d_in[10];
    const float* lng = (const float*)d_in[11];
    const float* lnb = (const float*)d_in[12];
    const float* pww = (const float*)d_in[13];
    const float* rpe = (const float*)d_in[14];
    float* out = (float*)d_out;

    float* ws   = (float*)d_ws;
    float* qbuf = ws;                       // 1572864
    float* posb = qbuf + 1572864;           // 12288
    float* xsb  = posb + 12288;             // 393216
    __half* ktb = (__half*)(xsb + 393216);  // 786 KB as fp16 (196608 float slots)
    float* vtb  = xsb + 393216 + 393216;    // 393216 [bh][s][32] fp32
    float* aout = vtb + 393216;             // 1572864
    float* cobuf = aout;                    // 393216, dead before attn writes aout

    conv1x1_mfma<CC_><<<dim3(HWSZ / 64, CC_ / 64, BB), 256, 0, stream>>>(Wq, bq, x, qbuf, HWSZ, CC_);
    offset_dw_kernel<<<dim3(NGC_, 24), 256, 0, stream>>>(qbuf, dww, dwb, cobuf);
    offset_fin_kernel<<<dim3(1536), 256, 0, stream>>>(cobuf, lng, lnb, pww, posb);
    sample_xs_kernel<<<dim3(NGC_, 24), 256, 0, stream>>>(x, posb, xsb);
    convkv_kernel<CC_><<<dim3(CC_ / 4, BB), 256, 0, stream>>>(Wk, bk, Wv, bv, xsb, ktb, vtb, NS_);
    attn_kernel<<<dim3(16, BB * NHD), 512, 0, stream>>>(qbuf, ktb, vtb, posb, rpe, aout);
    conv1x1_mfma<CC_><<<dim3(HWSZ / 64, CC_ / 64, BB), 256, 0, stream>>>(Wo, bo, aout, out, HWSZ, CC_);
}